// Round 1
// baseline (1328.112 us; speedup 1.0000x reference)
//
#include <hip/hip_runtime.h>
#include <math.h>

// Problem constants
#define BB 16
#define CC 512
#define HW 784
#define RR 32
#define NHD 8
#define HD 64
#define NT 784

// workspace layout (float offsets)
#define OFS_AVGP   0
#define OFS_MAXP   8192
#define OFS_CHS    16384
#define OFS_CMAX   24576
#define OFS_CMEAN  37120
#define OFS_SP     49664
#define OFS_P1     62208
#define OFS_ABAR   70400
#define OFS_XG     78592
#define XG_SZ      (BB*CC*HW)          // 6,422,528 floats
#define OFS_Q      (OFS_XG + XG_SZ)
#define OFS_K      (OFS_Q + XG_SZ)
#define OFS_V      (OFS_K + XG_SZ)

// ---------------- K1: per-(b,c) avg + max pooling over HW -------------------
__global__ void k_pool(const float* __restrict__ x, float* avg_p, float* max_p) {
  int wid = threadIdx.x >> 6;
  int lane = threadIdx.x & 63;
  int row = blockIdx.x * 4 + wid;                 // b*C + c, 8192 rows
  const float* xr = x + (size_t)row * HW;
  float s = 0.f, m = -INFINITY;
  for (int i = lane; i < HW; i += 64) { float v = xr[i]; s += v; m = fmaxf(m, v); }
  for (int o = 32; o; o >>= 1) { s += __shfl_down(s, o, 64); m = fmaxf(m, __shfl_down(m, o, 64)); }
  if (lane == 0) { avg_p[row] = s * (1.f/HW); max_p[row] = m; }
}

// ---------------- K2: channel-gate MLP, one block per batch -----------------
__global__ void k_chmlp(const float* avg_p, const float* max_p,
                        const float* w1, const float* b1,
                        const float* w2, const float* b2, float* chs) {
  __shared__ float pa[CC], pm[CC], hr[64];
  int b = blockIdx.x, t = threadIdx.x;
  for (int i = t; i < CC; i += 256) { pa[i] = avg_p[b*CC+i]; pm[i] = max_p[b*CC+i]; }
  __syncthreads();
  if (t < 64) {
    int r = t & 31;
    const float* src = (t < 32) ? pa : pm;
    float h = b1[r];
    const float* wr = w1 + r*CC;
    for (int c = 0; c < CC; c++) h += src[c]*wr[c];
    hr[t] = fmaxf(h, 0.f);
  }
  __syncthreads();
  for (int c = t; c < CC; c += 256) {
    float a = 2.f*b2[c];                          // b2 added by both mlp() calls
    const float* wr = w2 + c*RR;
    for (int r = 0; r < RR; r++) a += (hr[r]+hr[32+r])*wr[r];
    chs[b*CC+c] = 1.f/(1.f+__expf(-a));
  }
}

// ---- K3: apply channel gate, emit channel-max / channel-mean per pixel -----
__global__ void k_chgate(const float* __restrict__ x, const float* __restrict__ chs,
                         float* __restrict__ xg, float* cmax, float* cmean) {
  __shared__ float cs[CC];
  int b = blockIdx.x, t = threadIdx.x;
  for (int i = t; i < CC; i += 256) cs[i] = chs[b*CC+i];
  __syncthreads();
  int pix = blockIdx.y * 256 + t;
  if (pix >= HW) return;
  const float* xb = x + (size_t)b*CC*HW + pix;
  float* xgb = xg + (size_t)b*CC*HW + pix;
  float mx = -INFINITY, sm = 0.f;
  for (int c = 0; c < CC; c++) {
    float v = xb[(size_t)c*HW] * cs[c];
    xgb[(size_t)c*HW] = v;
    mx = fmaxf(mx, v); sm += v;
  }
  cmax[b*HW+pix] = mx; cmean[b*HW+pix] = sm*(1.f/CC);
}

// ---------------- K4: 7x7 spatial conv + BN(eval) + sigmoid -----------------
__global__ void k_spconv(const float* __restrict__ cmax, const float* __restrict__ cmean,
                         const float* __restrict__ w,
                         const float* g, const float* be, const float* mu, const float* var,
                         float* sp) {
  int b = blockIdx.x;
  int pix = blockIdx.y*256 + threadIdx.x;
  if (pix >= HW) return;
  int h = pix/28, wd = pix%28;
  float acc = 0.f;
  for (int kh = 0; kh < 7; kh++) {
    int ih = h + kh - 3; if (ih < 0 || ih >= 28) continue;
    for (int kw = 0; kw < 7; kw++) {
      int iw = wd + kw - 3; if (iw < 0 || iw >= 28) continue;
      int ip = ih*28+iw;
      acc += cmax[b*HW+ip]*w[kh*7+kw] + cmean[b*HW+ip]*w[49+kh*7+kw];
    }
  }
  float s = (acc - mu[0])*rsqrtf(var[0]+1e-5f)*g[0] + be[0];
  sp[b*HW+pix] = 1.f/(1.f+__expf(-s));
}

// ----- K5: apply spatial gate in place; p1[b,c] = mean_n of gated x ---------
__global__ void k_spgate(float* __restrict__ xg, const float* __restrict__ sp, float* p1) {
  int wid = threadIdx.x >> 6, lane = threadIdx.x & 63;
  int row = blockIdx.x*4 + wid;                   // b*C + c
  int b = row >> 9;
  float* xr = xg + (size_t)row*HW;
  const float* spb = sp + b*HW;
  float s = 0.f;
  for (int i = lane; i < HW; i += 64) { float v = xr[i]*spb[i]; xr[i] = v; s += v; }
  for (int o = 32; o; o >>= 1) s += __shfl_down(s, o, 64);
  if (lane == 0) p1[row] = s*(1.f/HW);
}

// ---------------- K6: QKV projection GEMM (fp32, 64x64 tiles) ---------------
// Out[n, c'] = sum_c xg[b, c, n] * W[c', c] + bias[c'], scattered to [b,h,n,d]
__global__ __launch_bounds__(256) void k_qkv(const float* __restrict__ xg,
    const float* __restrict__ wq, const float* __restrict__ bq,
    const float* __restrict__ wk, const float* __restrict__ bk,
    const float* __restrict__ wv, const float* __restrict__ bv,
    float* __restrict__ Qo, float* __restrict__ Ko, float* __restrict__ Vo) {
  __shared__ float As[16][64];
  __shared__ float Bs[16][64];
  int mt = blockIdx.x;                            // 0..12 (n tiles)
  int yt = blockIdx.y;                            // 0..23 = mat*8 + coltile
  int b  = blockIdx.z;
  int mat = yt >> 3, ct = yt & 7;
  const float* W; const float* bias; float* Out;
  if (mat == 0)      { W = wq; bias = bq; Out = Qo; }
  else if (mat == 1) { W = wk; bias = bk; Out = Ko; }
  else               { W = wv; bias = bv; Out = Vo; }
  int m0 = mt*64, c0 = ct*64;
  int t = threadIdx.x;
  int tx = t & 15, ty = t >> 4;
  float acc[4][4] = {};
  const float* Ab = xg + (size_t)b*CC*HW;
  for (int k0 = 0; k0 < CC; k0 += 16) {
    {
      int k = t >> 4, m = (t & 15)*4;
      const float* src = Ab + (size_t)(k0+k)*HW + m0 + m;
      float4 v;
      if (m0 + m + 3 < HW) v = *(const float4*)src;
      else {
        v.x = (m0+m+0 < HW)? src[0]:0.f;
        v.y = (m0+m+1 < HW)? src[1]:0.f;
        v.z = (m0+m+2 < HW)? src[2]:0.f;
        v.w = (m0+m+3 < HW)? src[3]:0.f;
      }
      *(float4*)&As[k][m] = v;
      int j = t >> 2, kk = (t & 3)*4;
      const float4 w4 = *(const float4*)(W + (size_t)(c0+j)*CC + k0 + kk);
      Bs[kk+0][j] = w4.x; Bs[kk+1][j] = w4.y; Bs[kk+2][j] = w4.z; Bs[kk+3][j] = w4.w;
    }
    __syncthreads();
    for (int k = 0; k < 16; k++) {
      float4 a4 = *(const float4*)&As[k][ty*4];
      float4 b4 = *(const float4*)&Bs[k][tx*4];
      float av[4] = {a4.x,a4.y,a4.z,a4.w};
      float bv4[4] = {b4.x,b4.y,b4.z,b4.w};
      for (int i = 0; i < 4; i++)
        for (int j = 0; j < 4; j++)
          acc[i][j] += av[i]*bv4[j];
    }
    __syncthreads();
  }
  for (int i = 0; i < 4; i++) {
    int n = m0 + ty*4 + i;
    if (n >= HW) continue;
    for (int j = 0; j < 4; j++) {
      int cc2 = c0 + tx*4 + j;
      int hh = cc2 >> 6, d = cc2 & 63;
      Out[(((size_t)b*NHD + hh)*NT + n)*HD + d] = acc[i][j] + bias[cc2];
    }
  }
}

// ------ K7: attention, one thread per query row; emits pooled abar ----------
#define KT 112
__global__ __launch_bounds__(256) void k_attn(const float* __restrict__ Q,
    const float* __restrict__ Km, const float* __restrict__ Vm,
    float* __restrict__ abar) {
  __shared__ float smem[2*KT*HD];                 // 14336 floats = 57.3 KB
  float* Ks = smem;
  float* Vs = smem + KT*HD;
  int bh = blockIdx.y;
  int t = threadIdx.x;
  int n = blockIdx.x*256 + t;
  bool act = (n < NT);
  const float4* qp = (const float4*)(Q + ((size_t)bh*NT + (act? n:0))*HD);
  float4 q4[16];
  for (int i = 0; i < 16; i++) q4[i] = act ? qp[i] : make_float4(0.f,0.f,0.f,0.f);
  float4 acc4[16];
  for (int i = 0; i < 16; i++) acc4[i] = make_float4(0.f,0.f,0.f,0.f);
  float l = 0.f;
  for (int m0 = 0; m0 < NT; m0 += KT) {
    const float4* ksrc = (const float4*)(Km + ((size_t)bh*NT + m0)*HD);
    const float4* vsrc = (const float4*)(Vm + ((size_t)bh*NT + m0)*HD);
    __syncthreads();
    for (int j = 0; j < 7; j++) {
      ((float4*)Ks)[j*256 + t] = ksrc[j*256 + t];
      ((float4*)Vs)[j*256 + t] = vsrc[j*256 + t];
    }
    __syncthreads();
    for (int m = 0; m < KT; m++) {
      const float4* kr = (const float4*)(Ks + m*HD);   // broadcast across lanes
      float s = 0.f;
      for (int i = 0; i < 16; i++) {
        float4 kv = kr[i];
        s += q4[i].x*kv.x + q4[i].y*kv.y + q4[i].z*kv.z + q4[i].w*kv.w;
      }
      float e = __expf(s * 0.125f);                    // scores tiny: no max-sub needed
      l += e;
      const float4* vr = (const float4*)(Vs + m*HD);
      for (int i = 0; i < 16; i++) {
        float4 vv = vr[i];
        acc4[i].x += e*vv.x; acc4[i].y += e*vv.y;
        acc4[i].z += e*vv.z; acc4[i].w += e*vv.w;
      }
    }
  }
  float scale = act ? (1.f/(l*(float)NT)) : 0.f;
  // block-reduce 64 per-thread values into abar[bh*64 + d], in two 32-d chunks
  for (int rep = 0; rep < 2; rep++) {
    __syncthreads();
    for (int i = 0; i < 8; i++) {
      float4 v = acc4[rep*8+i];
      smem[t + 256*(4*i+0)] = v.x*scale;
      smem[t + 256*(4*i+1)] = v.y*scale;
      smem[t + 256*(4*i+2)] = v.z*scale;
      smem[t + 256*(4*i+3)] = v.w*scale;
    }
    __syncthreads();
    for (int s = 128; s > 0; s >>= 1) {
      if (t < s)
        for (int j = 0; j < 32; j++)
          smem[t + 256*j] += smem[t + s + 256*j];
      __syncthreads();
    }
    if (t < 32) atomicAdd(&abar[bh*HD + rep*32 + t], smem[256*t]);
  }
}

// --------- K8: pooled head: wo-proj + LayerNorm + fc1/ReLU + fc2 ------------
__global__ void k_head(const float* __restrict__ p1, const float* __restrict__ abar,
                       const float* __restrict__ wo, const float* __restrict__ bo,
                       const float* __restrict__ ln_g, const float* __restrict__ ln_b,
                       const float* __restrict__ fc1_w, const float* __restrict__ fc1_b,
                       const float* __restrict__ fc2_w, const float* __restrict__ fc2_b,
                       float* __restrict__ out) {
  __shared__ float ab[CC], pv[CC], lnv[CC], h1[CC], red[64];
  int b = blockIdx.x, t = threadIdx.x;
  for (int i = t; i < CC; i += 256) ab[i] = abar[b*CC+i];
  __syncthreads();
  for (int c = t; c < CC; c += 256) {
    float a = bo[c] + p1[b*CC+c];
    const float* wr = wo + (size_t)c*CC;
    for (int j = 0; j < CC; j++) a += ab[j]*wr[j];
    pv[c] = a;
  }
  __syncthreads();
  float s = 0.f, s2 = 0.f;
  for (int i = t; i < CC; i += 256) { float v = pv[i]; s += v; s2 += v*v; }
  for (int o = 32; o; o >>= 1) { s += __shfl_down(s, o, 64); s2 += __shfl_down(s2, o, 64); }
  if ((t & 63) == 0) { red[t>>6] = s; red[4 + (t>>6)] = s2; }
  __syncthreads();
  float mean = (red[0]+red[1]+red[2]+red[3]) * (1.f/CC);
  float ex2  = (red[4]+red[5]+red[6]+red[7]) * (1.f/CC);
  float rs = rsqrtf(ex2 - mean*mean + 1e-5f);
  for (int i = t; i < CC; i += 256) lnv[i] = (pv[i]-mean)*rs*ln_g[i] + ln_b[i];
  __syncthreads();
  for (int j = t; j < CC; j += 256) {
    float a = fc1_b[j];
    const float* wr = fc1_w + (size_t)j*CC;
    for (int c = 0; c < CC; c++) a += lnv[c]*wr[c];
    h1[j] = fmaxf(a, 0.f);
  }
  __syncthreads();
  float o2 = 0.f;
  for (int j = t; j < CC; j += 256) o2 += h1[j]*fc2_w[j];
  for (int o = 32; o; o >>= 1) o2 += __shfl_down(o2, o, 64);
  if ((t & 63) == 0) red[8 + (t>>6)] = o2;
  __syncthreads();
  if (t == 0) out[b] = red[8]+red[9]+red[10]+red[11] + fc2_b[0];
}

extern "C" void kernel_launch(void* const* d_in, const int* in_sizes, int n_in,
                              void* d_out, int out_size, void* d_ws, size_t ws_size,
                              hipStream_t stream) {
  const float* x       = (const float*)d_in[0];
  const float* mlp_w1  = (const float*)d_in[1];
  const float* mlp_b1  = (const float*)d_in[2];
  const float* mlp_w2  = (const float*)d_in[3];
  const float* mlp_b2  = (const float*)d_in[4];
  const float* sp_w    = (const float*)d_in[5];
  const float* sp_g    = (const float*)d_in[6];
  const float* sp_b    = (const float*)d_in[7];
  const float* sp_mu   = (const float*)d_in[8];
  const float* sp_var  = (const float*)d_in[9];
  const float* wq      = (const float*)d_in[10];
  const float* bq      = (const float*)d_in[11];
  const float* wk      = (const float*)d_in[12];
  const float* bk      = (const float*)d_in[13];
  const float* wv      = (const float*)d_in[14];
  const float* bv      = (const float*)d_in[15];
  const float* wo      = (const float*)d_in[16];
  const float* bo      = (const float*)d_in[17];
  const float* ln_g    = (const float*)d_in[18];
  const float* ln_b    = (const float*)d_in[19];
  const float* fc1_w   = (const float*)d_in[20];
  const float* fc1_b   = (const float*)d_in[21];
  const float* fc2_w   = (const float*)d_in[22];
  const float* fc2_b   = (const float*)d_in[23];

  float* ws = (float*)d_ws;
  float* avg_p = ws + OFS_AVGP;
  float* max_p = ws + OFS_MAXP;
  float* chs   = ws + OFS_CHS;
  float* cmax  = ws + OFS_CMAX;
  float* cmean = ws + OFS_CMEAN;
  float* sp    = ws + OFS_SP;
  float* p1    = ws + OFS_P1;
  float* abar  = ws + OFS_ABAR;
  float* xg    = ws + OFS_XG;
  float* Qb    = ws + OFS_Q;
  float* Kb    = ws + OFS_K;
  float* Vb    = ws + OFS_V;

  hipMemsetAsync(abar, 0, BB*CC*sizeof(float), stream);   // atomic accumulator

  k_pool  <<<2048, 256, 0, stream>>>(x, avg_p, max_p);
  k_chmlp <<<BB, 256, 0, stream>>>(avg_p, max_p, mlp_w1, mlp_b1, mlp_w2, mlp_b2, chs);
  k_chgate<<<dim3(BB,4), 256, 0, stream>>>(x, chs, xg, cmax, cmean);
  k_spconv<<<dim3(BB,4), 256, 0, stream>>>(cmax, cmean, sp_w, sp_g, sp_b, sp_mu, sp_var, sp);
  k_spgate<<<2048, 256, 0, stream>>>(xg, sp, p1);
  k_qkv   <<<dim3(13,24,BB), 256, 0, stream>>>(xg, wq,bq, wk,bk, wv,bv, Qb, Kb, Vb);
  k_attn  <<<dim3(4,128), 256, 0, stream>>>(Qb, Kb, Vb, abar);
  k_head  <<<BB, 256, 0, stream>>>(p1, abar, wo, bo, ln_g, ln_b, fc1_w, fc1_b,
                                   fc2_w, fc2_b, (float*)d_out);
}

// Round 2
// 1200.567 us; speedup vs baseline: 1.1062x; 1.1062x over previous
//
#include <hip/hip_runtime.h>
#include <math.h>

// Problem constants
#define BB 16
#define CC 512
#define HW 784
#define RR 32
#define NHD 8
#define HD 64
#define NT 784

// workspace layout (float offsets)
#define OFS_AVGP   0
#define OFS_MAXP   8192
#define OFS_CHS    16384
#define OFS_CMAX   24576
#define OFS_CMEAN  37120
#define OFS_SP     49664
#define OFS_P1     62208
#define OFS_ABAR   70400
#define OFS_XG     78592
#define XG_SZ      (BB*CC*HW)          // 6,422,528 floats
#define OFS_Q      (OFS_XG + XG_SZ)
#define OFS_K      (OFS_Q + XG_SZ)
#define OFS_V      (OFS_K + XG_SZ)
// l and w overlay the (dead-after-k_qkv) xg region; zeroed after k_qkv runs.
#define OFS_L      OFS_XG
#define OFS_W      (OFS_XG + BB*NHD*NT)

// ---------------- K1: per-(b,c) avg + max pooling over HW -------------------
__global__ void k_pool(const float* __restrict__ x, float* avg_p, float* max_p) {
  int wid = threadIdx.x >> 6;
  int lane = threadIdx.x & 63;
  int row = blockIdx.x * 4 + wid;                 // b*C + c, 8192 rows
  const float* xr = x + (size_t)row * HW;
  float s = 0.f, m = -INFINITY;
  for (int i = lane; i < HW; i += 64) { float v = xr[i]; s += v; m = fmaxf(m, v); }
  for (int o = 32; o; o >>= 1) { s += __shfl_down(s, o, 64); m = fmaxf(m, __shfl_down(m, o, 64)); }
  if (lane == 0) { avg_p[row] = s * (1.f/HW); max_p[row] = m; }
}

// ---------------- K2: channel-gate MLP, one block per batch -----------------
__global__ void k_chmlp(const float* avg_p, const float* max_p,
                        const float* w1, const float* b1,
                        const float* w2, const float* b2, float* chs) {
  __shared__ float pa[CC], pm[CC], hr[64];
  int b = blockIdx.x, t = threadIdx.x;
  for (int i = t; i < CC; i += 256) { pa[i] = avg_p[b*CC+i]; pm[i] = max_p[b*CC+i]; }
  __syncthreads();
  if (t < 64) {
    int r = t & 31;
    const float* src = (t < 32) ? pa : pm;
    float h = b1[r];
    const float* wr = w1 + r*CC;
    for (int c = 0; c < CC; c++) h += src[c]*wr[c];
    hr[t] = fmaxf(h, 0.f);
  }
  __syncthreads();
  for (int c = t; c < CC; c += 256) {
    float a = 2.f*b2[c];                          // b2 added by both mlp() calls
    const float* wr = w2 + c*RR;
    for (int r = 0; r < RR; r++) a += (hr[r]+hr[32+r])*wr[r];
    chs[b*CC+c] = 1.f/(1.f+__expf(-a));
  }
}

// ---- K3: apply channel gate, emit channel-max / channel-mean per pixel -----
__global__ void k_chgate(const float* __restrict__ x, const float* __restrict__ chs,
                         float* __restrict__ xg, float* cmax, float* cmean) {
  __shared__ float cs[CC];
  int b = blockIdx.x, t = threadIdx.x;
  for (int i = t; i < CC; i += 256) cs[i] = chs[b*CC+i];
  __syncthreads();
  int pix = blockIdx.y * 256 + t;
  if (pix >= HW) return;
  const float* xb = x + (size_t)b*CC*HW + pix;
  float* xgb = xg + (size_t)b*CC*HW + pix;
  float mx = -INFINITY, sm = 0.f;
  for (int c = 0; c < CC; c++) {
    float v = xb[(size_t)c*HW] * cs[c];
    xgb[(size_t)c*HW] = v;
    mx = fmaxf(mx, v); sm += v;
  }
  cmax[b*HW+pix] = mx; cmean[b*HW+pix] = sm*(1.f/CC);
}

// ---------------- K4: 7x7 spatial conv + BN(eval) + sigmoid -----------------
__global__ void k_spconv(const float* __restrict__ cmax, const float* __restrict__ cmean,
                         const float* __restrict__ w,
                         const float* g, const float* be, const float* mu, const float* var,
                         float* sp) {
  int b = blockIdx.x;
  int pix = blockIdx.y*256 + threadIdx.x;
  if (pix >= HW) return;
  int h = pix/28, wd = pix%28;
  float acc = 0.f;
  for (int kh = 0; kh < 7; kh++) {
    int ih = h + kh - 3; if (ih < 0 || ih >= 28) continue;
    for (int kw = 0; kw < 7; kw++) {
      int iw = wd + kw - 3; if (iw < 0 || iw >= 28) continue;
      int ip = ih*28+iw;
      acc += cmax[b*HW+ip]*w[kh*7+kw] + cmean[b*HW+ip]*w[49+kh*7+kw];
    }
  }
  float s = (acc - mu[0])*rsqrtf(var[0]+1e-5f)*g[0] + be[0];
  sp[b*HW+pix] = 1.f/(1.f+__expf(-s));
}

// ----- K5: apply spatial gate in place; p1[b,c] = mean_n of gated x ---------
__global__ void k_spgate(float* __restrict__ xg, const float* __restrict__ sp, float* p1) {
  int wid = threadIdx.x >> 6, lane = threadIdx.x & 63;
  int row = blockIdx.x*4 + wid;                   // b*C + c
  int b = row >> 9;
  float* xr = xg + (size_t)row*HW;
  const float* spb = sp + b*HW;
  float s = 0.f;
  for (int i = lane; i < HW; i += 64) { float v = xr[i]*spb[i]; xr[i] = v; s += v; }
  for (int o = 32; o; o >>= 1) s += __shfl_down(s, o, 64);
  if (lane == 0) p1[row] = s*(1.f/HW);
}

// ---------------- K6: QKV projection GEMM (fp32, 64x64 tiles) ---------------
// Out[n, c'] = sum_c xg[b, c, n] * W[c', c] + bias[c'], scattered to [b,h,n,d]
__global__ __launch_bounds__(256) void k_qkv(const float* __restrict__ xg,
    const float* __restrict__ wq, const float* __restrict__ bq,
    const float* __restrict__ wk, const float* __restrict__ bk,
    const float* __restrict__ wv, const float* __restrict__ bv,
    float* __restrict__ Qo, float* __restrict__ Ko, float* __restrict__ Vo) {
  __shared__ float As[16][64];
  __shared__ float Bs[16][64];
  int mt = blockIdx.x;                            // 0..12 (n tiles)
  int yt = blockIdx.y;                            // 0..23 = mat*8 + coltile
  int b  = blockIdx.z;
  int mat = yt >> 3, ct = yt & 7;
  const float* W; const float* bias; float* Out;
  if (mat == 0)      { W = wq; bias = bq; Out = Qo; }
  else if (mat == 1) { W = wk; bias = bk; Out = Ko; }
  else               { W = wv; bias = bv; Out = Vo; }
  int m0 = mt*64, c0 = ct*64;
  int t = threadIdx.x;
  int tx = t & 15, ty = t >> 4;
  float acc[4][4] = {};
  const float* Ab = xg + (size_t)b*CC*HW;
  for (int k0 = 0; k0 < CC; k0 += 16) {
    {
      int k = t >> 4, m = (t & 15)*4;
      const float* src = Ab + (size_t)(k0+k)*HW + m0 + m;
      float4 v;
      if (m0 + m + 3 < HW) v = *(const float4*)src;
      else {
        v.x = (m0+m+0 < HW)? src[0]:0.f;
        v.y = (m0+m+1 < HW)? src[1]:0.f;
        v.z = (m0+m+2 < HW)? src[2]:0.f;
        v.w = (m0+m+3 < HW)? src[3]:0.f;
      }
      *(float4*)&As[k][m] = v;
      int j = t >> 2, kk = (t & 3)*4;
      const float4 w4 = *(const float4*)(W + (size_t)(c0+j)*CC + k0 + kk);
      Bs[kk+0][j] = w4.x; Bs[kk+1][j] = w4.y; Bs[kk+2][j] = w4.z; Bs[kk+3][j] = w4.w;
    }
    __syncthreads();
    for (int k = 0; k < 16; k++) {
      float4 a4 = *(const float4*)&As[k][ty*4];
      float4 b4 = *(const float4*)&Bs[k][tx*4];
      float av[4] = {a4.x,a4.y,a4.z,a4.w};
      float bv4[4] = {b4.x,b4.y,b4.z,b4.w};
      for (int i = 0; i < 4; i++)
        for (int j = 0; j < 4; j++)
          acc[i][j] += av[i]*bv4[j];
    }
    __syncthreads();
  }
  for (int i = 0; i < 4; i++) {
    int n = m0 + ty*4 + i;
    if (n >= HW) continue;
    for (int j = 0; j < 4; j++) {
      int cc2 = c0 + tx*4 + j;
      int hh = cc2 >> 6, d = cc2 & 63;
      Out[(((size_t)b*NHD + hh)*NT + n)*HD + d] = acc[i][j] + bias[cc2];
    }
  }
}

// ===================== attention via pooled-weight trick =====================
// abar[bh,d] = (1/N) sum_m w[m] V[m,d],  w[m] = sum_n exp(s_nm)/l_n
#define AKT 112

// ---- K7a: l_n = sum_m exp(q_n . k_m / 8). 2 queries/thread, keys in LDS ----
__global__ __launch_bounds__(256, 2) void k_attn_l(const float* __restrict__ Q,
    const float* __restrict__ Km, float* __restrict__ l) {
  __shared__ float Ks[AKT*HD];                    // 28 KB
  int bh = blockIdx.y;
  int t = threadIdx.x;
  int m0 = blockIdx.z * AKT;
  int n1 = blockIdx.x*512 + t;
  int n2 = n1 + 256;
  const float4* q1p = (const float4*)(Q + ((size_t)bh*NT + (n1 < NT ? n1 : 0))*HD);
  const float4* q2p = (const float4*)(Q + ((size_t)bh*NT + (n2 < NT ? n2 : 0))*HD);
  float4 qa[16], qb[16];
  #pragma unroll
  for (int i = 0; i < 16; i++) { qa[i] = q1p[i]; qb[i] = q2p[i]; }
  const float4* ksrc = (const float4*)(Km + ((size_t)bh*NT + m0)*HD);
  #pragma unroll
  for (int j = 0; j < 7; j++) ((float4*)Ks)[j*256 + t] = ksrc[j*256 + t];
  __syncthreads();
  float l1 = 0.f, l2 = 0.f;
  for (int m = 0; m < AKT; m++) {
    const float4* kr = (const float4*)(Ks + m*HD); // broadcast: conflict-free
    float s1a=0.f, s1b=0.f, s2a=0.f, s2b=0.f;
    #pragma unroll
    for (int i = 0; i < 16; i += 2) {
      float4 k0 = kr[i], k1 = kr[i+1];
      s1a += qa[i].x*k0.x + qa[i].y*k0.y + qa[i].z*k0.z + qa[i].w*k0.w;
      s1b += qa[i+1].x*k1.x + qa[i+1].y*k1.y + qa[i+1].z*k1.z + qa[i+1].w*k1.w;
      s2a += qb[i].x*k0.x + qb[i].y*k0.y + qb[i].z*k0.z + qb[i].w*k0.w;
      s2b += qb[i+1].x*k1.x + qb[i+1].y*k1.y + qb[i+1].z*k1.z + qb[i+1].w*k1.w;
    }
    l1 += __expf((s1a+s1b)*0.125f);
    l2 += __expf((s2a+s2b)*0.125f);
  }
  if (n1 < NT) atomicAdd(&l[bh*NT + n1], l1);
  if (n2 < NT) atomicAdd(&l[bh*NT + n2], l2);
}

// ---- K7b: w_m = sum_n exp(q_n . k_m / 8)/l_n. 2 keys/thread, Q in LDS ------
__global__ __launch_bounds__(256, 2) void k_attn_w(const float* __restrict__ Q,
    const float* __restrict__ Km, const float* __restrict__ l, float* __restrict__ w) {
  __shared__ float Qs[AKT*HD];                    // 28 KB
  __shared__ float Ls[AKT];
  int bh = blockIdx.y;
  int t = threadIdx.x;
  int n0 = blockIdx.z * AKT;
  int m1 = blockIdx.x*512 + t;
  int m2 = m1 + 256;
  const float4* k1p = (const float4*)(Km + ((size_t)bh*NT + (m1 < NT ? m1 : 0))*HD);
  const float4* k2p = (const float4*)(Km + ((size_t)bh*NT + (m2 < NT ? m2 : 0))*HD);
  float4 ka[16], kb[16];
  #pragma unroll
  for (int i = 0; i < 16; i++) { ka[i] = k1p[i]; kb[i] = k2p[i]; }
  const float4* qsrc = (const float4*)(Q + ((size_t)bh*NT + n0)*HD);
  #pragma unroll
  for (int j = 0; j < 7; j++) ((float4*)Qs)[j*256 + t] = qsrc[j*256 + t];
  if (t < AKT) Ls[t] = 1.0f / l[bh*NT + n0 + t];
  __syncthreads();
  float w1 = 0.f, w2 = 0.f;
  for (int n = 0; n < AKT; n++) {
    const float4* qr = (const float4*)(Qs + n*HD); // broadcast: conflict-free
    float s1a=0.f, s1b=0.f, s2a=0.f, s2b=0.f;
    #pragma unroll
    for (int i = 0; i < 16; i += 2) {
      float4 q0 = qr[i], q1 = qr[i+1];
      s1a += ka[i].x*q0.x + ka[i].y*q0.y + ka[i].z*q0.z + ka[i].w*q0.w;
      s1b += ka[i+1].x*q1.x + ka[i+1].y*q1.y + ka[i+1].z*q1.z + ka[i+1].w*q1.w;
      s2a += kb[i].x*q0.x + kb[i].y*q0.y + kb[i].z*q0.z + kb[i].w*q0.w;
      s2b += kb[i+1].x*q1.x + kb[i+1].y*q1.y + kb[i+1].z*q1.z + kb[i+1].w*q1.w;
    }
    float rl = Ls[n];
    w1 += __expf((s1a+s1b)*0.125f) * rl;
    w2 += __expf((s2a+s2b)*0.125f) * rl;
  }
  if (m1 < NT) atomicAdd(&w[bh*NT + m1], w1);
  if (m2 < NT) atomicAdd(&w[bh*NT + m2], w2);
}

// ---- K7c: abar[bh,d] = (1/N) sum_m w_m V[m,d] ------------------------------
__global__ void k_attn_av(const float* __restrict__ w, const float* __restrict__ Vm,
                          float* __restrict__ abar) {
  __shared__ float red[256];
  int bh = blockIdx.x, t = threadIdx.x;
  int d = t & 63, chunk = t >> 6;                 // 4 chunks of 196 keys
  float acc = 0.f;
  const float* vb = Vm + (size_t)bh*NT*HD;
  const float* wb = w + bh*NT;
  for (int m = chunk*196; m < (chunk+1)*196; m++)
    acc += wb[m] * vb[(size_t)m*HD + d];
  red[t] = acc;
  __syncthreads();
  if (t < 64)
    abar[bh*HD + t] = (red[t] + red[64+t] + red[128+t] + red[192+t]) * (1.f/NT);
}

// --------- K8: pooled head: wo-proj + LayerNorm + fc1/ReLU + fc2 ------------
__global__ void k_head(const float* __restrict__ p1, const float* __restrict__ abar,
                       const float* __restrict__ wo, const float* __restrict__ bo,
                       const float* __restrict__ ln_g, const float* __restrict__ ln_b,
                       const float* __restrict__ fc1_w, const float* __restrict__ fc1_b,
                       const float* __restrict__ fc2_w, const float* __restrict__ fc2_b,
                       float* __restrict__ out) {
  __shared__ float ab[CC], pv[CC], lnv[CC], h1[CC], red[64];
  int b = blockIdx.x, t = threadIdx.x;
  for (int i = t; i < CC; i += 256) ab[i] = abar[b*CC+i];
  __syncthreads();
  for (int c = t; c < CC; c += 256) {
    float a = bo[c] + p1[b*CC+c];
    const float* wr = wo + (size_t)c*CC;
    for (int j = 0; j < CC; j++) a += ab[j]*wr[j];
    pv[c] = a;
  }
  __syncthreads();
  float s = 0.f, s2 = 0.f;
  for (int i = t; i < CC; i += 256) { float v = pv[i]; s += v; s2 += v*v; }
  for (int o = 32; o; o >>= 1) { s += __shfl_down(s, o, 64); s2 += __shfl_down(s2, o, 64); }
  if ((t & 63) == 0) { red[t>>6] = s; red[4 + (t>>6)] = s2; }
  __syncthreads();
  float mean = (red[0]+red[1]+red[2]+red[3]) * (1.f/CC);
  float ex2  = (red[4]+red[5]+red[6]+red[7]) * (1.f/CC);
  float rs = rsqrtf(ex2 - mean*mean + 1e-5f);
  for (int i = t; i < CC; i += 256) lnv[i] = (pv[i]-mean)*rs*ln_g[i] + ln_b[i];
  __syncthreads();
  for (int j = t; j < CC; j += 256) {
    float a = fc1_b[j];
    const float* wr = fc1_w + (size_t)j*CC;
    for (int c = 0; c < CC; c++) a += lnv[c]*wr[c];
    h1[j] = fmaxf(a, 0.f);
  }
  __syncthreads();
  float o2 = 0.f;
  for (int j = t; j < CC; j += 256) o2 += h1[j]*fc2_w[j];
  for (int o = 32; o; o >>= 1) o2 += __shfl_down(o2, o, 64);
  if ((t & 63) == 0) red[8 + (t>>6)] = o2;
  __syncthreads();
  if (t == 0) out[b] = red[8]+red[9]+red[10]+red[11] + fc2_b[0];
}

extern "C" void kernel_launch(void* const* d_in, const int* in_sizes, int n_in,
                              void* d_out, int out_size, void* d_ws, size_t ws_size,
                              hipStream_t stream) {
  const float* x       = (const float*)d_in[0];
  const float* mlp_w1  = (const float*)d_in[1];
  const float* mlp_b1  = (const float*)d_in[2];
  const float* mlp_w2  = (const float*)d_in[3];
  const float* mlp_b2  = (const float*)d_in[4];
  const float* sp_w    = (const float*)d_in[5];
  const float* sp_g    = (const float*)d_in[6];
  const float* sp_b    = (const float*)d_in[7];
  const float* sp_mu   = (const float*)d_in[8];
  const float* sp_var  = (const float*)d_in[9];
  const float* wq      = (const float*)d_in[10];
  const float* bq      = (const float*)d_in[11];
  const float* wk      = (const float*)d_in[12];
  const float* bk      = (const float*)d_in[13];
  const float* wv      = (const float*)d_in[14];
  const float* bv      = (const float*)d_in[15];
  const float* wo      = (const float*)d_in[16];
  const float* bo      = (const float*)d_in[17];
  const float* ln_g    = (const float*)d_in[18];
  const float* ln_b    = (const float*)d_in[19];
  const float* fc1_w   = (const float*)d_in[20];
  const float* fc1_b   = (const float*)d_in[21];
  const float* fc2_w   = (const float*)d_in[22];
  const float* fc2_b   = (const float*)d_in[23];

  float* ws = (float*)d_ws;
  float* avg_p = ws + OFS_AVGP;
  float* max_p = ws + OFS_MAXP;
  float* chs   = ws + OFS_CHS;
  float* cmax  = ws + OFS_CMAX;
  float* cmean = ws + OFS_CMEAN;
  float* sp    = ws + OFS_SP;
  float* p1    = ws + OFS_P1;
  float* abar  = ws + OFS_ABAR;
  float* xg    = ws + OFS_XG;
  float* Qb    = ws + OFS_Q;
  float* Kb    = ws + OFS_K;
  float* Vb    = ws + OFS_V;
  float* lden  = ws + OFS_L;   // overlays xg (dead after k_qkv)
  float* wsum  = ws + OFS_W;   // overlays xg (dead after k_qkv)

  k_pool  <<<2048, 256, 0, stream>>>(x, avg_p, max_p);
  k_chmlp <<<BB, 256, 0, stream>>>(avg_p, max_p, mlp_w1, mlp_b1, mlp_w2, mlp_b2, chs);
  k_chgate<<<dim3(BB,4), 256, 0, stream>>>(x, chs, xg, cmax, cmean);
  k_spconv<<<dim3(BB,4), 256, 0, stream>>>(cmax, cmean, sp_w, sp_g, sp_b, sp_mu, sp_var, sp);
  k_spgate<<<2048, 256, 0, stream>>>(xg, sp, p1);
  k_qkv   <<<dim3(13,24,BB), 256, 0, stream>>>(xg, wq,bq, wk,bk, wv,bv, Qb, Kb, Vb);
  // xg is dead from here; overlay it with l/w accumulators (stream-ordered)
  hipMemsetAsync(lden, 0, BB*NHD*NT*sizeof(float), stream);
  hipMemsetAsync(wsum, 0, BB*NHD*NT*sizeof(float), stream);
  k_attn_l<<<dim3(2,128,7), 256, 0, stream>>>(Qb, Kb, lden);
  k_attn_w<<<dim3(2,128,7), 256, 0, stream>>>(Qb, Kb, lden, wsum);
  k_attn_av<<<128, 256, 0, stream>>>(wsum, Vb, abar);
  k_head  <<<BB, 256, 0, stream>>>(p1, abar, wo, bo, ln_g, ln_b, fc1_w, fc1_b,
                                   fc2_w, fc2_b, (float*)d_out);
}

// Round 3
// 607.078 us; speedup vs baseline: 2.1877x; 1.9776x over previous
//
#include <hip/hip_runtime.h>
#include <math.h>

// Problem constants
#define BB 16
#define CC 512
#define HW 784
#define RR 32
#define NHD 8
#define HD 64
#define NT 784

// workspace layout (float offsets)
#define OFS_AVGP   0
#define OFS_MAXP   8192
#define OFS_CHS    16384
#define OFS_CMAX   24576
#define OFS_CMEAN  37120
#define OFS_SP     49664
#define OFS_P1     62208
#define OFS_ABAR   70400
#define OFS_XG     78592
#define XG_SZ      (BB*CC*HW)          // 6,422,528 floats
#define OFS_Q      (OFS_XG + XG_SZ)
#define OFS_K      (OFS_Q + XG_SZ)
#define OFS_V      (OFS_K + XG_SZ)
// w overlays the (dead-after-k_qkv) xg region; zeroed after k_qkv runs.
#define OFS_W      (OFS_XG + BB*NHD*NT)

typedef __attribute__((ext_vector_type(8))) short bf16x8;
typedef __attribute__((ext_vector_type(4))) float f32x4;

__device__ __forceinline__ unsigned short f2bf(float x) {
  union { float f; unsigned u; } v; v.f = x;
  unsigned r = v.u + 0x7fffu + ((v.u >> 16) & 1u);
  return (unsigned short)(r >> 16);
}

// ---------------- K1: per-(b,c) avg + max pooling over HW -------------------
__global__ void k_pool(const float* __restrict__ x, float* avg_p, float* max_p) {
  int wid = threadIdx.x >> 6;
  int lane = threadIdx.x & 63;
  int row = blockIdx.x * 4 + wid;                 // b*C + c, 8192 rows
  const float* xr = x + (size_t)row * HW;
  float s = 0.f, m = -INFINITY;
  for (int i = lane; i < HW; i += 64) { float v = xr[i]; s += v; m = fmaxf(m, v); }
  for (int o = 32; o; o >>= 1) { s += __shfl_down(s, o, 64); m = fmaxf(m, __shfl_down(m, o, 64)); }
  if (lane == 0) { avg_p[row] = s * (1.f/HW); max_p[row] = m; }
}

// ---------------- K2: channel-gate MLP, one block per batch -----------------
__global__ void k_chmlp(const float* avg_p, const float* max_p,
                        const float* w1, const float* b1,
                        const float* w2, const float* b2, float* chs) {
  __shared__ float pa[CC], pm[CC], hr[64];
  int b = blockIdx.x, t = threadIdx.x;
  for (int i = t; i < CC; i += 256) { pa[i] = avg_p[b*CC+i]; pm[i] = max_p[b*CC+i]; }
  __syncthreads();
  if (t < 64) {
    int r = t & 31;
    const float* src = (t < 32) ? pa : pm;
    float h = b1[r];
    const float* wr = w1 + r*CC;
    for (int c = 0; c < CC; c++) h += src[c]*wr[c];
    hr[t] = fmaxf(h, 0.f);
  }
  __syncthreads();
  for (int c = t; c < CC; c += 256) {
    float a = 2.f*b2[c];                          // b2 added by both mlp() calls
    const float* wr = w2 + c*RR;
    for (int r = 0; r < RR; r++) a += (hr[r]+hr[32+r])*wr[r];
    chs[b*CC+c] = 1.f/(1.f+__expf(-a));
  }
}

// ---- K3: apply channel gate, emit channel-max / channel-mean per pixel -----
__global__ void k_chgate(const float* __restrict__ x, const float* __restrict__ chs,
                         float* __restrict__ xg, float* cmax, float* cmean) {
  __shared__ float cs[CC];
  int b = blockIdx.x, t = threadIdx.x;
  for (int i = t; i < CC; i += 256) cs[i] = chs[b*CC+i];
  __syncthreads();
  int pix = blockIdx.y * 256 + t;
  if (pix >= HW) return;
  const float* xb = x + (size_t)b*CC*HW + pix;
  float* xgb = xg + (size_t)b*CC*HW + pix;
  float mx = -INFINITY, sm = 0.f;
  for (int c = 0; c < CC; c++) {
    float v = xb[(size_t)c*HW] * cs[c];
    xgb[(size_t)c*HW] = v;
    mx = fmaxf(mx, v); sm += v;
  }
  cmax[b*HW+pix] = mx; cmean[b*HW+pix] = sm*(1.f/CC);
}

// ---------------- K4: 7x7 spatial conv + BN(eval) + sigmoid -----------------
__global__ void k_spconv(const float* __restrict__ cmax, const float* __restrict__ cmean,
                         const float* __restrict__ w,
                         const float* g, const float* be, const float* mu, const float* var,
                         float* sp) {
  int b = blockIdx.x;
  int pix = blockIdx.y*256 + threadIdx.x;
  if (pix >= HW) return;
  int h = pix/28, wd = pix%28;
  float acc = 0.f;
  for (int kh = 0; kh < 7; kh++) {
    int ih = h + kh - 3; if (ih < 0 || ih >= 28) continue;
    for (int kw = 0; kw < 7; kw++) {
      int iw = wd + kw - 3; if (iw < 0 || iw >= 28) continue;
      int ip = ih*28+iw;
      acc += cmax[b*HW+ip]*w[kh*7+kw] + cmean[b*HW+ip]*w[49+kh*7+kw];
    }
  }
  float s = (acc - mu[0])*rsqrtf(var[0]+1e-5f)*g[0] + be[0];
  sp[b*HW+pix] = 1.f/(1.f+__expf(-s));
}

// ----- K5: apply spatial gate in place; p1[b,c] = mean_n of gated x ---------
__global__ void k_spgate(float* __restrict__ xg, const float* __restrict__ sp, float* p1) {
  int wid = threadIdx.x >> 6, lane = threadIdx.x & 63;
  int row = blockIdx.x*4 + wid;                   // b*C + c
  int b = row >> 9;
  float* xr = xg + (size_t)row*HW;
  const float* spb = sp + b*HW;
  float s = 0.f;
  for (int i = lane; i < HW; i += 64) { float v = xr[i]*spb[i]; xr[i] = v; s += v; }
  for (int o = 32; o; o >>= 1) s += __shfl_down(s, o, 64);
  if (lane == 0) p1[row] = s*(1.f/HW);
}

// ---------------- K6: QKV projection GEMM (fp32, 64x64 tiles) ---------------
// Out[n, c'] = sum_c xg[b, c, n] * W[c', c] + bias[c'], scattered to [b,h,n,d]
__global__ __launch_bounds__(256) void k_qkv(const float* __restrict__ xg,
    const float* __restrict__ wq, const float* __restrict__ bq,
    const float* __restrict__ wk, const float* __restrict__ bk,
    const float* __restrict__ wv, const float* __restrict__ bv,
    float* __restrict__ Qo, float* __restrict__ Ko, float* __restrict__ Vo) {
  __shared__ float As[16][64];
  __shared__ float Bs[16][64];
  int mt = blockIdx.x;                            // 0..12 (n tiles)
  int yt = blockIdx.y;                            // 0..23 = mat*8 + coltile
  int b  = blockIdx.z;
  int mat = yt >> 3, ct = yt & 7;
  const float* W; const float* bias; float* Out;
  if (mat == 0)      { W = wq; bias = bq; Out = Qo; }
  else if (mat == 1) { W = wk; bias = bk; Out = Ko; }
  else               { W = wv; bias = bv; Out = Vo; }
  int m0 = mt*64, c0 = ct*64;
  int t = threadIdx.x;
  int tx = t & 15, ty = t >> 4;
  float acc[4][4] = {};
  const float* Ab = xg + (size_t)b*CC*HW;
  for (int k0 = 0; k0 < CC; k0 += 16) {
    {
      int k = t >> 4, m = (t & 15)*4;
      const float* src = Ab + (size_t)(k0+k)*HW + m0 + m;
      float4 v;
      if (m0 + m + 3 < HW) v = *(const float4*)src;
      else {
        v.x = (m0+m+0 < HW)? src[0]:0.f;
        v.y = (m0+m+1 < HW)? src[1]:0.f;
        v.z = (m0+m+2 < HW)? src[2]:0.f;
        v.w = (m0+m+3 < HW)? src[3]:0.f;
      }
      *(float4*)&As[k][m] = v;
      int j = t >> 2, kk = (t & 3)*4;
      const float4 w4 = *(const float4*)(W + (size_t)(c0+j)*CC + k0 + kk);
      Bs[kk+0][j] = w4.x; Bs[kk+1][j] = w4.y; Bs[kk+2][j] = w4.z; Bs[kk+3][j] = w4.w;
    }
    __syncthreads();
    for (int k = 0; k < 16; k++) {
      float4 a4 = *(const float4*)&As[k][ty*4];
      float4 b4 = *(const float4*)&Bs[k][tx*4];
      float av[4] = {a4.x,a4.y,a4.z,a4.w};
      float bv4[4] = {b4.x,b4.y,b4.z,b4.w};
      for (int i = 0; i < 4; i++)
        for (int j = 0; j < 4; j++)
          acc[i][j] += av[i]*bv4[j];
    }
    __syncthreads();
  }
  for (int i = 0; i < 4; i++) {
    int n = m0 + ty*4 + i;
    if (n >= HW) continue;
    for (int j = 0; j < 4; j++) {
      int cc2 = c0 + tx*4 + j;
      int hh = cc2 >> 6, d = cc2 & 63;
      Out[(((size_t)b*NHD + hh)*NT + n)*HD + d] = acc[i][j] + bias[cc2];
    }
  }
}

// ============ K7: fused MFMA attention -> w_m (pooled-weight trick) =========
// abar[bh,d] = (1/N) sum_m w[m] V[m,d],  w[m] = sum_n exp(s_nm)/l_n
// One block per (n-quarter, bh). Q quarter + K chunk staged in LDS in
// fragment-ready bf16 layout: chunk(tile,half,lane) holds
// M[tile*16 + (lane&15)][half*32 + (lane>>4)*8 .. +8] as bf16x8 at
// offset (tile*128 + half*64 + lane)*16B  -> lane-contiguous ds_read_b128.
__device__ __forceinline__ void stage_frags(const float* __restrict__ src,
                                            int row0, int ntiles,
                                            unsigned short* dst, int t) {
  int nchunks = ntiles * 128;
  for (int c = t; c < nchunks; c += 256) {
    int lt   = c >> 7;
    int rem  = c & 127;
    int half = rem >> 6;
    int ln   = rem & 63;
    int row  = row0 + lt*16 + (ln & 15);
    int k    = half*32 + (ln >> 4)*8;
    const float* s = src + (size_t)row*HD + k;
    float4 f0 = *(const float4*)s;
    float4 f1 = *(const float4*)(s + 4);
    bf16x8 p;
    p[0]=(short)f2bf(f0.x); p[1]=(short)f2bf(f0.y); p[2]=(short)f2bf(f0.z); p[3]=(short)f2bf(f0.w);
    p[4]=(short)f2bf(f1.x); p[5]=(short)f2bf(f1.y); p[6]=(short)f2bf(f1.z); p[7]=(short)f2bf(f1.w);
    *(bf16x8*)(dst + (size_t)c*8) = p;
  }
}

__global__ __launch_bounds__(256, 2) void k_attn_fused(const float* __restrict__ Q,
    const float* __restrict__ K, float* __restrict__ wsum) {
  __shared__ __align__(16) unsigned short Qs[13*1024];
  __shared__ __align__(16) unsigned short Ks[13*1024];
  __shared__ float l_lds[13*16];
  const int qb[5] = {0,13,25,37,49};
  int quarter = blockIdx.x, bh = blockIdx.y;
  int t = threadIdx.x, w = t >> 6, lane = t & 63;
  int nt0 = qb[quarter], ntq = qb[quarter+1] - nt0;
  const float* Qb = Q + (size_t)bh*NT*HD;
  const float* Kb = K + (size_t)bh*NT*HD;
  stage_frags(Qb, nt0*16, ntq, Qs, t);            // Q quarter, resident whole kernel

  float l_regs[4][4];
  #pragma unroll
  for (int i = 0; i < 4; i++)
    #pragma unroll
    for (int r = 0; r < 4; r++) l_regs[i][r] = 0.f;

  // ---- pass 1: l_n (per-lane column-partials, reduced once at the end) ----
  for (int ch = 0; ch < 4; ch++) {
    int mt0 = qb[0] + ch*13; if (ch == 3) mt0 = 39;
    int mta = (ch < 3) ? 13 : 10;                 // chunks: 13,13,13,10
    mt0 = ch*13;
    __syncthreads();
    stage_frags(Kb, mt0*16, mta, Ks, t);
    __syncthreads();
    #pragma unroll
    for (int idx = 0; idx < 4; idx++) {
      int nt = w + idx*4;
      if (nt < ntq) {
        bf16x8 aq0 = ((const bf16x8*)Qs)[nt*128 + lane];
        bf16x8 aq1 = ((const bf16x8*)Qs)[nt*128 + 64 + lane];
        for (int mt = 0; mt < mta; mt++) {
          bf16x8 bk0 = ((const bf16x8*)Ks)[mt*128 + lane];
          bf16x8 bk1 = ((const bf16x8*)Ks)[mt*128 + 64 + lane];
          f32x4 acc = {0.f, 0.f, 0.f, 0.f};
          acc = __builtin_amdgcn_mfma_f32_16x16x32_bf16(aq0, bk0, acc, 0, 0, 0);
          acc = __builtin_amdgcn_mfma_f32_16x16x32_bf16(aq1, bk1, acc, 0, 0, 0);
          l_regs[idx][0] += __expf(acc[0]*0.125f);
          l_regs[idx][1] += __expf(acc[1]*0.125f);
          l_regs[idx][2] += __expf(acc[2]*0.125f);
          l_regs[idx][3] += __expf(acc[3]*0.125f);
        }
      }
    }
  }
  // reduce l across the 16 column-lanes; C layout: row n = (lane>>4)*4+r
  #pragma unroll
  for (int idx = 0; idx < 4; idx++) {
    int nt = w + idx*4;
    if (nt < ntq) {
      #pragma unroll
      for (int r = 0; r < 4; r++) {
        float v = l_regs[idx][r];
        v += __shfl_xor(v, 1, 64);
        v += __shfl_xor(v, 2, 64);
        v += __shfl_xor(v, 4, 64);
        v += __shfl_xor(v, 8, 64);
        if ((lane & 15) == 0) l_lds[nt*16 + (lane>>4)*4 + r] = v;
      }
    }
  }
  __syncthreads();
  if (t < ntq*16) l_lds[t] = 1.f / l_lds[t];

  // ---- pass 2: w_m partials over this block's n-range (A=K, B=Q) ----------
  for (int ch = 0; ch < 4; ch++) {
    int mt0 = ch*13;
    int mta = (ch < 3) ? 13 : 10;
    __syncthreads();
    stage_frags(Kb, mt0*16, mta, Ks, t);
    __syncthreads();
    #pragma unroll
    for (int idx = 0; idx < 4; idx++) {
      int mt = w + idx*4;
      if (mt < mta) {
        bf16x8 ak0 = ((const bf16x8*)Ks)[mt*128 + lane];
        bf16x8 ak1 = ((const bf16x8*)Ks)[mt*128 + 64 + lane];
        float w0 = 0.f, w1 = 0.f, w2 = 0.f, w3 = 0.f;
        for (int nt = 0; nt < ntq; nt++) {
          bf16x8 bq0 = ((const bf16x8*)Qs)[nt*128 + lane];
          bf16x8 bq1 = ((const bf16x8*)Qs)[nt*128 + 64 + lane];
          f32x4 acc = {0.f, 0.f, 0.f, 0.f};
          acc = __builtin_amdgcn_mfma_f32_16x16x32_bf16(ak0, bq0, acc, 0, 0, 0);
          acc = __builtin_amdgcn_mfma_f32_16x16x32_bf16(ak1, bq1, acc, 0, 0, 0);
          float rl = l_lds[nt*16 + (lane & 15)];  // 1/l_n, n = col = lane&15
          w0 += __expf(acc[0]*0.125f) * rl;
          w1 += __expf(acc[1]*0.125f) * rl;
          w2 += __expf(acc[2]*0.125f) * rl;
          w3 += __expf(acc[3]*0.125f) * rl;
        }
        // reduce across the 16 n-lanes; C row = key m = (lane>>4)*4 + r
        w0 += __shfl_xor(w0,1,64); w0 += __shfl_xor(w0,2,64); w0 += __shfl_xor(w0,4,64); w0 += __shfl_xor(w0,8,64);
        w1 += __shfl_xor(w1,1,64); w1 += __shfl_xor(w1,2,64); w1 += __shfl_xor(w1,4,64); w1 += __shfl_xor(w1,8,64);
        w2 += __shfl_xor(w2,1,64); w2 += __shfl_xor(w2,2,64); w2 += __shfl_xor(w2,4,64); w2 += __shfl_xor(w2,8,64);
        w3 += __shfl_xor(w3,1,64); w3 += __shfl_xor(w3,2,64); w3 += __shfl_xor(w3,4,64); w3 += __shfl_xor(w3,8,64);
        if ((lane & 15) == 0) {
          int m = (mt0 + mt)*16 + (lane>>4)*4;
          atomicAdd(&wsum[bh*NT + m + 0], w0);
          atomicAdd(&wsum[bh*NT + m + 1], w1);
          atomicAdd(&wsum[bh*NT + m + 2], w2);
          atomicAdd(&wsum[bh*NT + m + 3], w3);
        }
      }
    }
  }
}

// ---- K7c: abar[bh,d] = (1/N) sum_m w_m V[m,d] ------------------------------
__global__ void k_attn_av(const float* __restrict__ w, const float* __restrict__ Vm,
                          float* __restrict__ abar) {
  __shared__ float red[256];
  int bh = blockIdx.x, t = threadIdx.x;
  int d = t & 63, chunk = t >> 6;                 // 4 chunks of 196 keys
  float acc = 0.f;
  const float* vb = Vm + (size_t)bh*NT*HD;
  const float* wb = w + bh*NT;
  for (int m = chunk*196; m < (chunk+1)*196; m++)
    acc += wb[m] * vb[(size_t)m*HD + d];
  red[t] = acc;
  __syncthreads();
  if (t < 64)
    abar[bh*HD + t] = (red[t] + red[64+t] + red[128+t] + red[192+t]) * (1.f/NT);
}

// --------- K8: pooled head: wo-proj + LayerNorm + fc1/ReLU + fc2 ------------
__global__ void k_head(const float* __restrict__ p1, const float* __restrict__ abar,
                       const float* __restrict__ wo, const float* __restrict__ bo,
                       const float* __restrict__ ln_g, const float* __restrict__ ln_b,
                       const float* __restrict__ fc1_w, const float* __restrict__ fc1_b,
                       const float* __restrict__ fc2_w, const float* __restrict__ fc2_b,
                       float* __restrict__ out) {
  __shared__ float ab[CC], pv[CC], lnv[CC], h1[CC], red[64];
  int b = blockIdx.x, t = threadIdx.x;
  for (int i = t; i < CC; i += 256) ab[i] = abar[b*CC+i];
  __syncthreads();
  for (int c = t; c < CC; c += 256) {
    float a = bo[c] + p1[b*CC+c];
    const float* wr = wo + (size_t)c*CC;
    for (int j = 0; j < CC; j++) a += ab[j]*wr[j];
    pv[c] = a;
  }
  __syncthreads();
  float s = 0.f, s2 = 0.f;
  for (int i = t; i < CC; i += 256) { float v = pv[i]; s += v; s2 += v*v; }
  for (int o = 32; o; o >>= 1) { s += __shfl_down(s, o, 64); s2 += __shfl_down(s2, o, 64); }
  if ((t & 63) == 0) { red[t>>6] = s; red[4 + (t>>6)] = s2; }
  __syncthreads();
  float mean = (red[0]+red[1]+red[2]+red[3]) * (1.f/CC);
  float ex2  = (red[4]+red[5]+red[6]+red[7]) * (1.f/CC);
  float rs = rsqrtf(ex2 - mean*mean + 1e-5f);
  for (int i = t; i < CC; i += 256) lnv[i] = (pv[i]-mean)*rs*ln_g[i] + ln_b[i];
  __syncthreads();
  for (int j = t; j < CC; j += 256) {
    float a = fc1_b[j];
    const float* wr = fc1_w + (size_t)j*CC;
    for (int c = 0; c < CC; c++) a += lnv[c]*wr[c];
    h1[j] = fmaxf(a, 0.f);
  }
  __syncthreads();
  float o2 = 0.f;
  for (int j = t; j < CC; j += 256) o2 += h1[j]*fc2_w[j];
  for (int o = 32; o; o >>= 1) o2 += __shfl_down(o2, o, 64);
  if ((t & 63) == 0) red[8 + (t>>6)] = o2;
  __syncthreads();
  if (t == 0) out[b] = red[8]+red[9]+red[10]+red[11] + fc2_b[0];
}

extern "C" void kernel_launch(void* const* d_in, const int* in_sizes, int n_in,
                              void* d_out, int out_size, void* d_ws, size_t ws_size,
                              hipStream_t stream) {
  const float* x       = (const float*)d_in[0];
  const float* mlp_w1  = (const float*)d_in[1];
  const float* mlp_b1  = (const float*)d_in[2];
  const float* mlp_w2  = (const float*)d_in[3];
  const float* mlp_b2  = (const float*)d_in[4];
  const float* sp_w    = (const float*)d_in[5];
  const float* sp_g    = (const float*)d_in[6];
  const float* sp_b    = (const float*)d_in[7];
  const float* sp_mu   = (const float*)d_in[8];
  const float* sp_var  = (const float*)d_in[9];
  const float* wq      = (const float*)d_in[10];
  const float* bq      = (const float*)d_in[11];
  const float* wk      = (const float*)d_in[12];
  const float* bk      = (const float*)d_in[13];
  const float* wv      = (const float*)d_in[14];
  const float* bv      = (const float*)d_in[15];
  const float* wo      = (const float*)d_in[16];
  const float* bo      = (const float*)d_in[17];
  const float* ln_g    = (const float*)d_in[18];
  const float* ln_b    = (const float*)d_in[19];
  const float* fc1_w   = (const float*)d_in[20];
  const float* fc1_b   = (const float*)d_in[21];
  const float* fc2_w   = (const float*)d_in[22];
  const float* fc2_b   = (const float*)d_in[23];

  float* ws = (float*)d_ws;
  float* avg_p = ws + OFS_AVGP;
  float* max_p = ws + OFS_MAXP;
  float* chs   = ws + OFS_CHS;
  float* cmax  = ws + OFS_CMAX;
  float* cmean = ws + OFS_CMEAN;
  float* sp    = ws + OFS_SP;
  float* p1    = ws + OFS_P1;
  float* abar  = ws + OFS_ABAR;
  float* xg    = ws + OFS_XG;
  float* Qb    = ws + OFS_Q;
  float* Kb    = ws + OFS_K;
  float* Vb    = ws + OFS_V;
  float* wsum  = ws + OFS_W;   // overlays xg (dead after k_qkv)

  k_pool  <<<2048, 256, 0, stream>>>(x, avg_p, max_p);
  k_chmlp <<<BB, 256, 0, stream>>>(avg_p, max_p, mlp_w1, mlp_b1, mlp_w2, mlp_b2, chs);
  k_chgate<<<dim3(BB,4), 256, 0, stream>>>(x, chs, xg, cmax, cmean);
  k_spconv<<<dim3(BB,4), 256, 0, stream>>>(cmax, cmean, sp_w, sp_g, sp_b, sp_mu, sp_var, sp);
  k_spgate<<<2048, 256, 0, stream>>>(xg, sp, p1);
  k_qkv   <<<dim3(13,24,BB), 256, 0, stream>>>(xg, wq,bq, wk,bk, wv,bv, Qb, Kb, Vb);
  // xg is dead from here; overlay it with the w accumulator (stream-ordered)
  hipMemsetAsync(wsum, 0, BB*NHD*NT*sizeof(float), stream);
  k_attn_fused<<<dim3(4,128), 256, 0, stream>>>(Qb, Kb, wsum);
  k_attn_av<<<128, 256, 0, stream>>>(wsum, Vb, abar);
  k_head  <<<BB, 256, 0, stream>>>(p1, abar, wo, bo, ln_g, ln_b, fc1_w, fc1_b,
                                   fc2_w, fc2_b, (float*)d_out);
}

// Round 4
// 392.423 us; speedup vs baseline: 3.3844x; 1.5470x over previous
//
#include <hip/hip_runtime.h>
#include <math.h>

// Problem constants
#define BB 16
#define CC 512
#define HW 784
#define RR 32
#define NHD 8
#define HD 64
#define NT 784
#define NTILE 49                       // 784 = 49 * 16 n-tiles

// workspace layout (float offsets)
#define OFS_AVGP   0
#define OFS_MAXP   8192
#define OFS_CHS    16384
#define OFS_CMAX   24576
#define OFS_CMEAN  37120
#define OFS_SP     49664
#define OFS_P1     62208
#define OFS_ABAR   70400
#define OFS_XG     78592
#define XG_SZ      (BB*CC*HW)          // 6,422,528 floats
#define OFS_XGT    (OFS_XG + XG_SZ)            // bf16 frag xg^T  (XG_SZ bf16)
#define OFS_QBF    (OFS_XGT + XG_SZ/2)         // bf16 frag Q     (XG_SZ bf16)
#define OFS_KBF    (OFS_QBF + XG_SZ/2)         // bf16 frag K     (XG_SZ bf16)
#define OFS_V2     (OFS_KBF + XG_SZ/2)         // fp32 V [bh][n][d]
#define OFS_WF     (OFS_V2 + XG_SZ)            // bf16 frag weights (786432 bf16)
// wsum overlays the (dead-after-k_xgT) xg region
#define OFS_W      OFS_XG

typedef __attribute__((ext_vector_type(8))) short bf16x8;
typedef __attribute__((ext_vector_type(4))) float f32x4;

__device__ __forceinline__ unsigned short f2bf(float x) {
  union { float f; unsigned u; } v; v.f = x;
  unsigned r = v.u + 0x7fffu + ((v.u >> 16) & 1u);
  return (unsigned short)(r >> 16);
}

// ---------------- K1: per-(b,c) avg + max pooling over HW -------------------
__global__ void k_pool(const float* __restrict__ x, float* avg_p, float* max_p) {
  int wid = threadIdx.x >> 6;
  int lane = threadIdx.x & 63;
  int row = blockIdx.x * 4 + wid;                 // b*C + c, 8192 rows
  const float* xr = x + (size_t)row * HW;
  float s = 0.f, m = -INFINITY;
  for (int i = lane; i < HW; i += 64) { float v = xr[i]; s += v; m = fmaxf(m, v); }
  for (int o = 32; o; o >>= 1) { s += __shfl_down(s, o, 64); m = fmaxf(m, __shfl_down(m, o, 64)); }
  if (lane == 0) { avg_p[row] = s * (1.f/HW); max_p[row] = m; }
}

// ---------------- K2: channel-gate MLP, one block per batch -----------------
__global__ void k_chmlp(const float* avg_p, const float* max_p,
                        const float* w1, const float* b1,
                        const float* w2, const float* b2, float* chs) {
  __shared__ float pa[CC], pm[CC], hr[64];
  int b = blockIdx.x, t = threadIdx.x;
  for (int i = t; i < CC; i += 256) { pa[i] = avg_p[b*CC+i]; pm[i] = max_p[b*CC+i]; }
  __syncthreads();
  if (t < 64) {
    int r = t & 31;
    const float* src = (t < 32) ? pa : pm;
    float h = b1[r];
    const float* wr = w1 + r*CC;
    for (int c = 0; c < CC; c++) h += src[c]*wr[c];
    hr[t] = fmaxf(h, 0.f);
  }
  __syncthreads();
  for (int c = t; c < CC; c += 256) {
    float a = 2.f*b2[c];                          // b2 added by both mlp() calls
    const float* wr = w2 + c*RR;
    for (int r = 0; r < RR; r++) a += (hr[r]+hr[32+r])*wr[r];
    chs[b*CC+c] = 1.f/(1.f+__expf(-a));
  }
}

// ---- K3: apply channel gate, emit channel-max / channel-mean per pixel -----
__global__ void k_chgate(const float* __restrict__ x, const float* __restrict__ chs,
                         float* __restrict__ xg, float* cmax, float* cmean) {
  __shared__ float cs[CC];
  int b = blockIdx.x, t = threadIdx.x;
  for (int i = t; i < CC; i += 256) cs[i] = chs[b*CC+i];
  __syncthreads();
  int pix = blockIdx.y * 256 + t;
  if (pix >= HW) return;
  const float* xb = x + (size_t)b*CC*HW + pix;
  float* xgb = xg + (size_t)b*CC*HW + pix;
  float mx = -INFINITY, sm = 0.f;
  for (int c = 0; c < CC; c++) {
    float v = xb[(size_t)c*HW] * cs[c];
    xgb[(size_t)c*HW] = v;
    mx = fmaxf(mx, v); sm += v;
  }
  cmax[b*HW+pix] = mx; cmean[b*HW+pix] = sm*(1.f/CC);
}

// ---------------- K4: 7x7 spatial conv + BN(eval) + sigmoid -----------------
__global__ void k_spconv(const float* __restrict__ cmax, const float* __restrict__ cmean,
                         const float* __restrict__ w,
                         const float* g, const float* be, const float* mu, const float* var,
                         float* sp) {
  int b = blockIdx.x;
  int pix = blockIdx.y*256 + threadIdx.x;
  if (pix >= HW) return;
  int h = pix/28, wd = pix%28;
  float acc = 0.f;
  for (int kh = 0; kh < 7; kh++) {
    int ih = h + kh - 3; if (ih < 0 || ih >= 28) continue;
    for (int kw = 0; kw < 7; kw++) {
      int iw = wd + kw - 3; if (iw < 0 || iw >= 28) continue;
      int ip = ih*28+iw;
      acc += cmax[b*HW+ip]*w[kh*7+kw] + cmean[b*HW+ip]*w[49+kh*7+kw];
    }
  }
  float s = (acc - mu[0])*rsqrtf(var[0]+1e-5f)*g[0] + be[0];
  sp[b*HW+pix] = 1.f/(1.f+__expf(-s));
}

// ----- K5: apply spatial gate in place; p1[b,c] = mean_n of gated x ---------
__global__ void k_spgate(float* __restrict__ xg, const float* __restrict__ sp, float* p1) {
  int wid = threadIdx.x >> 6, lane = threadIdx.x & 63;
  int row = blockIdx.x*4 + wid;                   // b*C + c
  int b = row >> 9;
  float* xr = xg + (size_t)row*HW;
  const float* spb = sp + b*HW;
  float s = 0.f;
  for (int i = lane; i < HW; i += 64) { float v = xr[i]*spb[i]; xr[i] = v; s += v; }
  for (int o = 32; o; o >>= 1) s += __shfl_down(s, o, 64);
  if (lane == 0) p1[row] = s*(1.f/HW);
}

// ---- K5b: gather gated xg into fragment-ready bf16 xgT --------------------
// chunk (b, nt, s, ln): token n = nt*16+(ln&15), k = s*32+(ln>>4)*8 .. +8
__global__ void k_xgT(const float* __restrict__ xg, unsigned short* __restrict__ xgT) {
  int nt = blockIdx.x;                            // 0..48
  int b  = blockIdx.y;
  int t = threadIdx.x, ln = t & 63;
  const float* xb = xg + (size_t)b*CC*HW;
  #pragma unroll
  for (int i = 0; i < 4; i++) {
    int s = (t >> 6) + 4*i;
    int n = nt*16 + (ln & 15);
    int c = s*32 + (ln >> 4)*8;
    bf16x8 p;
    #pragma unroll
    for (int j = 0; j < 8; j++) p[j] = (short)f2bf(xb[(size_t)(c+j)*HW + n]);
    *(bf16x8*)(xgT + ((((size_t)b*NTILE + nt)*16 + s)*64 + ln)*8) = p;
  }
}

// ---- K5c: reformat wq/wk/wv into fragment-ready bf16 ----------------------
// chunk idx = ((mat*32 + ct)*16 + s)*64 + ln: c' = ct*16+(ln&15), k = s*32+(ln>>4)*8
__global__ void k_wfrag(const float* __restrict__ wq, const float* __restrict__ wk,
                        const float* __restrict__ wv, unsigned short* __restrict__ Wf) {
  int idx = blockIdx.x*256 + threadIdx.x;         // 98304 chunks
  int ln = idx & 63;
  int s  = (idx >> 6) & 15;
  int ct = (idx >> 10) & 31;
  int mat = idx >> 15;
  const float* W = (mat==0)? wq : (mat==1)? wk : wv;
  const float* src = W + (size_t)(ct*16 + (ln & 15))*CC + s*32 + (ln >> 4)*8;
  float4 f0 = *(const float4*)src;
  float4 f1 = *(const float4*)(src + 4);
  bf16x8 p;
  p[0]=(short)f2bf(f0.x); p[1]=(short)f2bf(f0.y); p[2]=(short)f2bf(f0.z); p[3]=(short)f2bf(f0.w);
  p[4]=(short)f2bf(f1.x); p[5]=(short)f2bf(f1.y); p[6]=(short)f2bf(f1.z); p[7]=(short)f2bf(f1.w);
  *(bf16x8*)(Wf + (size_t)idx*8) = p;
}

// ---------------- K6: QKV projection — pure-MFMA, no LDS in K-loop ----------
// block: 64 n x 128 c'; wave w owns c' [w*32, w*32+32); outputs Q/K as bf16
// fragments, V as fp32 [bh][n][d].
__global__ __launch_bounds__(256) void k_qkv_mfma(
    const unsigned short* __restrict__ xgT, const unsigned short* __restrict__ Wf,
    const float* __restrict__ bq, const float* __restrict__ bk, const float* __restrict__ bv,
    unsigned short* __restrict__ Qbf, unsigned short* __restrict__ Kbf,
    float* __restrict__ Vf) {
  __shared__ float Cb[64*132];                    // padded bounce tile (33.8 KB)
  int mt = blockIdx.x;                            // 0..12: n-tiles 4mt..4mt+3
  int yb = blockIdx.y;                            // 0..11: mat=yb>>2, c0=(yb&3)*128
  int b  = blockIdx.z;
  int mat = yb >> 2;
  int c0 = (yb & 3) * 128;
  int t = threadIdx.x, w = t >> 6, ln = t & 63;
  const unsigned short* Ab = xgT + (size_t)b*NTILE*8192;
  const unsigned short* Bb = Wf + (size_t)mat*32*8192;
  int ctg0 = (c0 >> 4) + w*2;
  f32x4 acc[4][2];
  #pragma unroll
  for (int m = 0; m < 4; m++)
    #pragma unroll
    for (int c2 = 0; c2 < 2; c2++) acc[m][c2] = (f32x4){0.f,0.f,0.f,0.f};
  int ntc[4];
  #pragma unroll
  for (int m = 0; m < 4; m++) { int nt = 4*mt + m; ntc[m] = (nt > 48) ? 48 : nt; }
  for (int s = 0; s < 16; s++) {
    bf16x8 bf0 = *(const bf16x8*)(Bb + (size_t)(ctg0*16 + s)*512 + ln*8);
    bf16x8 bf1 = *(const bf16x8*)(Bb + (size_t)((ctg0+1)*16 + s)*512 + ln*8);
    bf16x8 af[4];
    #pragma unroll
    for (int m = 0; m < 4; m++)
      af[m] = *(const bf16x8*)(Ab + (size_t)(ntc[m]*16 + s)*512 + ln*8);
    #pragma unroll
    for (int m = 0; m < 4; m++) {
      acc[m][0] = __builtin_amdgcn_mfma_f32_16x16x32_bf16(af[m], bf0, acc[m][0], 0,0,0);
      acc[m][1] = __builtin_amdgcn_mfma_f32_16x16x32_bf16(af[m], bf1, acc[m][1], 0,0,0);
    }
  }
  // bounce: C rows n-local = m*16+(ln>>4)*4+r, cols c'-local = w*32+c2*16+(ln&15)
  #pragma unroll
  for (int m = 0; m < 4; m++)
    #pragma unroll
    for (int c2 = 0; c2 < 2; c2++)
      #pragma unroll
      for (int r = 0; r < 4; r++)
        Cb[(m*16 + (ln>>4)*4 + r)*132 + w*32 + c2*16 + (ln&15)] = acc[m][c2][r];
  __syncthreads();
  const float* bias = (mat==0)? bq : (mat==1)? bk : bv;
  #pragma unroll
  for (int i = 0; i < 4; i++) {
    int p = w*4 + i;                              // 16 (ntl, sl) pairs
    int ntl = p >> 2, sl = p & 3;
    int nt = 4*mt + ntl;
    if (nt > 48) continue;
    int row = ntl*16 + (ln & 15);
    int col = sl*32 + (ln >> 4)*8;
    float v[8];
    #pragma unroll
    for (int j = 0; j < 8; j++) v[j] = Cb[row*132 + col + j] + bias[c0 + col + j];
    int token = nt*16 + (ln & 15);
    int h = (c0 >> 6) + (sl >> 1);
    int bh = b*NHD + h;
    if (mat < 2) {
      bf16x8 pk;
      #pragma unroll
      for (int j = 0; j < 8; j++) pk[j] = (short)f2bf(v[j]);
      unsigned short* Out = (mat == 0) ? Qbf : Kbf;
      *(bf16x8*)(Out + ((size_t)bh*NTILE + nt)*1024 + (size_t)(sl & 1)*512 + ln*8) = pk;
    } else {
      int d = (sl & 1)*32 + (ln >> 4)*8;
      float* dst = Vf + ((size_t)bh*NT + token)*HD + d;
      *(float4*)dst = make_float4(v[0], v[1], v[2], v[3]);
      *(float4*)(dst + 4) = make_float4(v[4], v[5], v[6], v[7]);
    }
  }
}

// ---------------- K7: MFMA attention, fragments straight from global --------
// abar[bh,d] = (1/N) sum_m w[m] V[m,d],  w[m] = sum_n exp(s_nm)/l_n
__global__ __launch_bounds__(256) void k_attn2(const unsigned short* __restrict__ Qbf,
    const unsigned short* __restrict__ Kbf, float* __restrict__ wsum) {
  __shared__ float l_lds[7*16];
  const int qb0[9] = {0,7,13,19,25,31,37,43,49};
  int g8 = blockIdx.x, bh = blockIdx.y;
  int t = threadIdx.x, w = t >> 6, ln = t & 63;
  int nt0 = qb0[g8], ntq = qb0[g8+1] - nt0;
  const unsigned short* Qb = Qbf + (size_t)bh*NTILE*1024;
  const unsigned short* Kb = Kbf + (size_t)bh*NTILE*1024;

  // ---- pass 1: l_n for this block's n-group (wave owns tiles w, w+4) ------
  int nA = nt0 + w;
  bool hasB = (w + 4) < ntq;
  int nB = nt0 + (hasB ? (w + 4) : w);
  bf16x8 qA0 = *(const bf16x8*)(Qb + (size_t)(nA*2+0)*512 + ln*8);
  bf16x8 qA1 = *(const bf16x8*)(Qb + (size_t)(nA*2+1)*512 + ln*8);
  bf16x8 qB0 = *(const bf16x8*)(Qb + (size_t)(nB*2+0)*512 + ln*8);
  bf16x8 qB1 = *(const bf16x8*)(Qb + (size_t)(nB*2+1)*512 + ln*8);
  float lA[4] = {0.f,0.f,0.f,0.f}, lB[4] = {0.f,0.f,0.f,0.f};
  for (int mt = 0; mt < NTILE; mt++) {
    bf16x8 k0 = *(const bf16x8*)(Kb + (size_t)(mt*2+0)*512 + ln*8);
    bf16x8 k1 = *(const bf16x8*)(Kb + (size_t)(mt*2+1)*512 + ln*8);
    f32x4 a = {0.f,0.f,0.f,0.f};
    a = __builtin_amdgcn_mfma_f32_16x16x32_bf16(qA0, k0, a, 0,0,0);
    a = __builtin_amdgcn_mfma_f32_16x16x32_bf16(qA1, k1, a, 0,0,0);
    f32x4 c = {0.f,0.f,0.f,0.f};
    c = __builtin_amdgcn_mfma_f32_16x16x32_bf16(qB0, k0, c, 0,0,0);
    c = __builtin_amdgcn_mfma_f32_16x16x32_bf16(qB1, k1, c, 0,0,0);
    #pragma unroll
    for (int r = 0; r < 4; r++) {
      lA[r] += __expf(a[r]*0.125f);
      lB[r] += __expf(c[r]*0.125f);
    }
  }
  #pragma unroll
  for (int r = 0; r < 4; r++) {
    float v = lA[r];
    v += __shfl_xor(v,1,64); v += __shfl_xor(v,2,64);
    v += __shfl_xor(v,4,64); v += __shfl_xor(v,8,64);
    if ((ln & 15) == 0) l_lds[(nA-nt0)*16 + (ln>>4)*4 + r] = v;
    float u = lB[r];
    u += __shfl_xor(u,1,64); u += __shfl_xor(u,2,64);
    u += __shfl_xor(u,4,64); u += __shfl_xor(u,8,64);
    if (hasB && (ln & 15) == 0) l_lds[(nB-nt0)*16 + (ln>>4)*4 + r] = u;
  }
  __syncthreads();
  if (t < ntq*16) l_lds[t] = 1.f / l_lds[t];
  __syncthreads();

  // ---- pass 2: w_m partials over this n-group (A=K, B=Q) ------------------
  for (int mt = w; mt < NTILE; mt += 4) {
    bf16x8 a0 = *(const bf16x8*)(Kb + (size_t)(mt*2+0)*512 + ln*8);
    bf16x8 a1 = *(const bf16x8*)(Kb + (size_t)(mt*2+1)*512 + ln*8);
    float w0 = 0.f, w1 = 0.f, w2 = 0.f, w3 = 0.f;
    for (int j = 0; j < ntq; j++) {
      int nt = nt0 + j;
      bf16x8 b0 = *(const bf16x8*)(Qb + (size_t)(nt*2+0)*512 + ln*8);
      bf16x8 b1 = *(const bf16x8*)(Qb + (size_t)(nt*2+1)*512 + ln*8);
      f32x4 a = {0.f,0.f,0.f,0.f};
      a = __builtin_amdgcn_mfma_f32_16x16x32_bf16(a0, b0, a, 0,0,0);
      a = __builtin_amdgcn_mfma_f32_16x16x32_bf16(a1, b1, a, 0,0,0);
      float rl = l_lds[j*16 + (ln & 15)];
      w0 += __expf(a[0]*0.125f) * rl;
      w1 += __expf(a[1]*0.125f) * rl;
      w2 += __expf(a[2]*0.125f) * rl;
      w3 += __expf(a[3]*0.125f) * rl;
    }
    w0 += __shfl_xor(w0,1,64); w0 += __shfl_xor(w0,2,64); w0 += __shfl_xor(w0,4,64); w0 += __shfl_xor(w0,8,64);
    w1 += __shfl_xor(w1,1,64); w1 += __shfl_xor(w1,2,64); w1 += __shfl_xor(w1,4,64); w1 += __shfl_xor(w1,8,64);
    w2 += __shfl_xor(w2,1,64); w2 += __shfl_xor(w2,2,64); w2 += __shfl_xor(w2,4,64); w2 += __shfl_xor(w2,8,64);
    w3 += __shfl_xor(w3,1,64); w3 += __shfl_xor(w3,2,64); w3 += __shfl_xor(w3,4,64); w3 += __shfl_xor(w3,8,64);
    if ((ln & 15) == 0) {
      int m = mt*16 + (ln>>4)*4;
      atomicAdd(&wsum[bh*NT + m + 0], w0);
      atomicAdd(&wsum[bh*NT + m + 1], w1);
      atomicAdd(&wsum[bh*NT + m + 2], w2);
      atomicAdd(&wsum[bh*NT + m + 3], w3);
    }
  }
}

// ---- K7c: abar[bh,d] = (1/N) sum_m w_m V[m,d] ------------------------------
__global__ void k_attn_av(const float* __restrict__ w, const float* __restrict__ Vm,
                          float* __restrict__ abar) {
  __shared__ float red[256];
  int bh = blockIdx.x, t = threadIdx.x;
  int d = t & 63, chunk = t >> 6;                 // 4 chunks of 196 keys
  float acc = 0.f;
  const float* vb = Vm + (size_t)bh*NT*HD;
  const float* wb = w + bh*NT;
  for (int m = chunk*196; m < (chunk+1)*196; m++)
    acc += wb[m] * vb[(size_t)m*HD + d];
  red[t] = acc;
  __syncthreads();
  if (t < 64)
    abar[bh*HD + t] = (red[t] + red[64+t] + red[128+t] + red[192+t]) * (1.f/NT);
}

// --------- K8: pooled head: wo-proj + LayerNorm + fc1/ReLU + fc2 ------------
__global__ void k_head(const float* __restrict__ p1, const float* __restrict__ abar,
                       const float* __restrict__ wo, const float* __restrict__ bo,
                       const float* __restrict__ ln_g, const float* __restrict__ ln_b,
                       const float* __restrict__ fc1_w, const float* __restrict__ fc1_b,
                       const float* __restrict__ fc2_w, const float* __restrict__ fc2_b,
                       float* __restrict__ out) {
  __shared__ float ab[CC], pv[CC], lnv[CC], h1[CC], red[64];
  int b = blockIdx.x, t = threadIdx.x;
  for (int i = t; i < CC; i += 256) ab[i] = abar[b*CC+i];
  __syncthreads();
  for (int c = t; c < CC; c += 256) {
    float a = bo[c] + p1[b*CC+c];
    const float* wr = wo + (size_t)c*CC;
    for (int j = 0; j < CC; j++) a += ab[j]*wr[j];
    pv[c] = a;
  }
  __syncthreads();
  float s = 0.f, s2 = 0.f;
  for (int i = t; i < CC; i += 256) { float v = pv[i]; s += v; s2 += v*v; }
  for (int o = 32; o; o >>= 1) { s += __shfl_down(s, o, 64); s2 += __shfl_down(s2, o, 64); }
  if ((t & 63) == 0) { red[t>>6] = s; red[4 + (t>>6)] = s2; }
  __syncthreads();
  float mean = (red[0]+red[1]+red[2]+red[3]) * (1.f/CC);
  float ex2  = (red[4]+red[5]+red[6]+red[7]) * (1.f/CC);
  float rs = rsqrtf(ex2 - mean*mean + 1e-5f);
  for (int i = t; i < CC; i += 256) lnv[i] = (pv[i]-mean)*rs*ln_g[i] + ln_b[i];
  __syncthreads();
  for (int j = t; j < CC; j += 256) {
    float a = fc1_b[j];
    const float* wr = fc1_w + (size_t)j*CC;
    for (int c = 0; c < CC; c++) a += lnv[c]*wr[c];
    h1[j] = fmaxf(a, 0.f);
  }
  __syncthreads();
  float o2 = 0.f;
  for (int j = t; j < CC; j += 256) o2 += h1[j]*fc2_w[j];
  for (int o = 32; o; o >>= 1) o2 += __shfl_down(o2, o, 64);
  if ((t & 63) == 0) red[8 + (t>>6)] = o2;
  __syncthreads();
  if (t == 0) out[b] = red[8]+red[9]+red[10]+red[11] + fc2_b[0];
}

extern "C" void kernel_launch(void* const* d_in, const int* in_sizes, int n_in,
                              void* d_out, int out_size, void* d_ws, size_t ws_size,
                              hipStream_t stream) {
  const float* x       = (const float*)d_in[0];
  const float* mlp_w1  = (const float*)d_in[1];
  const float* mlp_b1  = (const float*)d_in[2];
  const float* mlp_w2  = (const float*)d_in[3];
  const float* mlp_b2  = (const float*)d_in[4];
  const float* sp_w    = (const float*)d_in[5];
  const float* sp_g    = (const float*)d_in[6];
  const float* sp_b    = (const float*)d_in[7];
  const float* sp_mu   = (const float*)d_in[8];
  const float* sp_var  = (const float*)d_in[9];
  const float* wq      = (const float*)d_in[10];
  const float* bq      = (const float*)d_in[11];
  const float* wk      = (const float*)d_in[12];
  const float* bk      = (const float*)d_in[13];
  const float* wv      = (const float*)d_in[14];
  const float* bv      = (const float*)d_in[15];
  const float* wo      = (const float*)d_in[16];
  const float* bo      = (const float*)d_in[17];
  const float* ln_g    = (const float*)d_in[18];
  const float* ln_b    = (const float*)d_in[19];
  const float* fc1_w   = (const float*)d_in[20];
  const float* fc1_b   = (const float*)d_in[21];
  const float* fc2_w   = (const float*)d_in[22];
  const float* fc2_b   = (const float*)d_in[23];

  float* ws = (float*)d_ws;
  float* avg_p = ws + OFS_AVGP;
  float* max_p = ws + OFS_MAXP;
  float* chs   = ws + OFS_CHS;
  float* cmax  = ws + OFS_CMAX;
  float* cmean = ws + OFS_CMEAN;
  float* sp    = ws + OFS_SP;
  float* p1    = ws + OFS_P1;
  float* abar  = ws + OFS_ABAR;
  float* xg    = ws + OFS_XG;
  unsigned short* xgT = (unsigned short*)(ws + OFS_XGT);
  unsigned short* Qbf = (unsigned short*)(ws + OFS_QBF);
  unsigned short* Kbf = (unsigned short*)(ws + OFS_KBF);
  float* Vf    = ws + OFS_V2;
  unsigned short* Wf  = (unsigned short*)(ws + OFS_WF);
  float* wsum  = ws + OFS_W;   // overlays xg (dead after k_xgT)

  k_pool  <<<2048, 256, 0, stream>>>(x, avg_p, max_p);
  k_chmlp <<<BB, 256, 0, stream>>>(avg_p, max_p, mlp_w1, mlp_b1, mlp_w2, mlp_b2, chs);
  k_chgate<<<dim3(BB,4), 256, 0, stream>>>(x, chs, xg, cmax, cmean);
  k_spconv<<<dim3(BB,4), 256, 0, stream>>>(cmax, cmean, sp_w, sp_g, sp_b, sp_mu, sp_var, sp);
  k_spgate<<<2048, 256, 0, stream>>>(xg, sp, p1);
  k_wfrag <<<384, 256, 0, stream>>>(wq, wk, wv, Wf);
  k_xgT   <<<dim3(NTILE,BB), 256, 0, stream>>>(xg, xgT);
  k_qkv_mfma<<<dim3(13,12,BB), 256, 0, stream>>>(xgT, Wf, bq, bk, bv, Qbf, Kbf, Vf);
  // xg is dead from here; overlay it with the w accumulator (stream-ordered)
  hipMemsetAsync(wsum, 0, BB*NHD*NT*sizeof(float), stream);
  k_attn2 <<<dim3(8,128), 256, 0, stream>>>(Qbf, Kbf, wsum);
  k_attn_av<<<128, 256, 0, stream>>>(wsum, Vf, abar);
  k_head  <<<BB, 256, 0, stream>>>(p1, abar, wo, bo, ln_g, ln_b, fc1_w, fc1_b,
                                   fc2_w, fc2_b, (float*)d_out);
}

// Round 5
// 342.012 us; speedup vs baseline: 3.8832x; 1.1474x over previous
//
#include <hip/hip_runtime.h>
#include <math.h>

// Problem constants
#define BB 16
#define CC 512
#define HW 784
#define RR 32
#define NHD 8
#define HD 64
#define NT 784
#define NTILE 49                       // 784 = 49 * 16 n-tiles

// workspace layout (float offsets)
#define OFS_AVGP   0
#define OFS_MAXP   8192
#define OFS_CHS    16384
#define OFS_CMAX   24576
#define OFS_CMEAN  37120
#define OFS_SP     49664
#define OFS_P1     62208
#define OFS_ABAR   70400
#define OFS_XG     78592
#define XG_SZ      (BB*CC*HW)          // 6,422,528 floats (region reused below)
#define OFS_XGT    (OFS_XG + XG_SZ)            // bf16 frag xg^T  (XG_SZ bf16)
#define OFS_QBF    (OFS_XGT + XG_SZ/2)         // bf16 frag Q     (XG_SZ bf16)
#define OFS_KBF    (OFS_QBF + XG_SZ/2)         // bf16 frag K     (XG_SZ bf16)
#define OFS_V2     (OFS_KBF + XG_SZ/2)         // fp32 V [bh][n][d]
#define OFS_WF     (OFS_V2 + XG_SZ)            // bf16 frag weights (786432 bf16)
// overlays inside the dead xg region:
#define OFS_W      OFS_XG                      // wsum   (100352 floats)
#define OFS_PV     (OFS_XG + 131072)           // pv     (8192)
#define OFS_LNV    (OFS_PV + 8192)             // lnv    (8192)
#define OFS_H1     (OFS_LNV + 8192)            // h1     (8192)

typedef __attribute__((ext_vector_type(8))) short bf16x8;
typedef __attribute__((ext_vector_type(4))) float f32x4;

__device__ __forceinline__ unsigned short f2bf(float x) {
  union { float f; unsigned u; } v; v.f = x;
  unsigned r = v.u + 0x7fffu + ((v.u >> 16) & 1u);
  return (unsigned short)(r >> 16);
}

// ---------------- K1: per-(b,c) avg + max pooling over HW -------------------
__global__ void k_pool(const float* __restrict__ x, float* avg_p, float* max_p) {
  int wid = threadIdx.x >> 6;
  int lane = threadIdx.x & 63;
  int row = blockIdx.x * 4 + wid;                 // b*C + c, 8192 rows
  const float* xr = x + (size_t)row * HW;
  float s = 0.f, m = -INFINITY;
  for (int i = lane; i < HW; i += 64) { float v = xr[i]; s += v; m = fmaxf(m, v); }
  for (int o = 32; o; o >>= 1) { s += __shfl_down(s, o, 64); m = fmaxf(m, __shfl_down(m, o, 64)); }
  if (lane == 0) { avg_p[row] = s * (1.f/HW); max_p[row] = m; }
}

// ---------------- K2: channel-gate MLP, one block per batch -----------------
__global__ void k_chmlp(const float* avg_p, const float* max_p,
                        const float* w1, const float* b1,
                        const float* w2, const float* b2, float* chs) {
  __shared__ float pa[CC], pm[CC], hr[64];
  int b = blockIdx.x, t = threadIdx.x;
  for (int i = t; i < CC; i += 256) { pa[i] = avg_p[b*CC+i]; pm[i] = max_p[b*CC+i]; }
  __syncthreads();
  if (t < 64) {
    int r = t & 31;
    const float* src = (t < 32) ? pa : pm;
    float h = b1[r];
    const float* wr = w1 + r*CC;
    for (int c = 0; c < CC; c++) h += src[c]*wr[c];
    hr[t] = fmaxf(h, 0.f);
  }
  __syncthreads();
  for (int c = t; c < CC; c += 256) {
    float a = 2.f*b2[c];                          // b2 added by both mlp() calls
    const float* wr = w2 + c*RR;
    for (int r = 0; r < RR; r++) a += (hr[r]+hr[32+r])*wr[r];
    chs[b*CC+c] = 1.f/(1.f+__expf(-a));
  }
}

// ---- K3: channel gate -> per-pixel channel-max / channel-mean only ---------
__global__ void k_chgate2(const float* __restrict__ x, const float* __restrict__ chs,
                          float* cmax, float* cmean) {
  __shared__ float cs[CC];
  int b = blockIdx.x, t = threadIdx.x;
  for (int i = t; i < CC; i += 256) cs[i] = chs[b*CC+i];
  __syncthreads();
  int pix = blockIdx.y * 256 + t;
  if (pix >= HW) return;
  const float* xb = x + (size_t)b*CC*HW + pix;
  float mx = -INFINITY, sm = 0.f;
  for (int c = 0; c < CC; c++) {
    float v = xb[(size_t)c*HW] * cs[c];
    mx = fmaxf(mx, v); sm += v;
  }
  cmax[b*HW+pix] = mx; cmean[b*HW+pix] = sm*(1.f/CC);
}

// ---------------- K4: 7x7 spatial conv + BN(eval) + sigmoid -----------------
__global__ void k_spconv(const float* __restrict__ cmax, const float* __restrict__ cmean,
                         const float* __restrict__ w,
                         const float* g, const float* be, const float* mu, const float* var,
                         float* sp) {
  int b = blockIdx.x;
  int pix = blockIdx.y*256 + threadIdx.x;
  if (pix >= HW) return;
  int h = pix/28, wd = pix%28;
  float acc = 0.f;
  for (int kh = 0; kh < 7; kh++) {
    int ih = h + kh - 3; if (ih < 0 || ih >= 28) continue;
    for (int kw = 0; kw < 7; kw++) {
      int iw = wd + kw - 3; if (iw < 0 || iw >= 28) continue;
      int ip = ih*28+iw;
      acc += cmax[b*HW+ip]*w[kh*7+kw] + cmean[b*HW+ip]*w[49+kh*7+kw];
    }
  }
  float s = (acc - mu[0])*rsqrtf(var[0]+1e-5f)*g[0] + be[0];
  sp[b*HW+pix] = 1.f/(1.f+__expf(-s));
}

// ---- K5: fused gates -> fragment-ready bf16 xgT + pooled p1 ----------------
// v = x[b,c,n]*chs[c]*sp[n]. chunk (b, nt, s, ln): n = nt*16+(ln&15),
// c = s*32+(ln>>4)*8 .. +8. p1[b][c] = mean_n v via 16-lane reduce + atomics.
__global__ void k_sfuse(const float* __restrict__ x, const float* __restrict__ chs,
                        const float* __restrict__ sp, unsigned short* __restrict__ xgT,
                        float* __restrict__ p1) {
  __shared__ float cs[CC];
  int nt = blockIdx.x, b = blockIdx.y;
  int t = threadIdx.x, ln = t & 63;
  for (int i = t; i < CC; i += 256) cs[i] = chs[b*CC+i];
  __syncthreads();
  int n = nt*16 + (ln & 15);
  float spv = sp[b*HW + n];
  const float* xb = x + (size_t)b*CC*HW;
  #pragma unroll
  for (int i = 0; i < 4; i++) {
    int s = (t >> 6) + 4*i;
    int c = s*32 + (ln >> 4)*8;
    float v[8]; bf16x8 p;
    #pragma unroll
    for (int j = 0; j < 8; j++) {
      v[j] = xb[(size_t)(c+j)*HW + n] * cs[c+j] * spv;
      p[j] = (short)f2bf(v[j]);
    }
    *(bf16x8*)(xgT + ((((size_t)b*NTILE + nt)*16 + s)*64 + ln)*8) = p;
    #pragma unroll
    for (int j = 0; j < 8; j++) {
      float sv = v[j];
      sv += __shfl_xor(sv, 1, 64); sv += __shfl_xor(sv, 2, 64);
      sv += __shfl_xor(sv, 4, 64); sv += __shfl_xor(sv, 8, 64);
      if ((ln & 15) == 0) atomicAdd(&p1[b*CC + c + j], sv * (1.f/HW));
    }
  }
}

// ---- K5c: reformat wq/wk/wv into fragment-ready bf16 ----------------------
__global__ void k_wfrag(const float* __restrict__ wq, const float* __restrict__ wk,
                        const float* __restrict__ wv, unsigned short* __restrict__ Wf) {
  int idx = blockIdx.x*256 + threadIdx.x;         // 98304 chunks
  int ln = idx & 63;
  int s  = (idx >> 6) & 15;
  int ct = (idx >> 10) & 31;
  int mat = idx >> 15;
  const float* W = (mat==0)? wq : (mat==1)? wk : wv;
  const float* src = W + (size_t)(ct*16 + (ln & 15))*CC + s*32 + (ln >> 4)*8;
  float4 f0 = *(const float4*)src;
  float4 f1 = *(const float4*)(src + 4);
  bf16x8 p;
  p[0]=(short)f2bf(f0.x); p[1]=(short)f2bf(f0.y); p[2]=(short)f2bf(f0.z); p[3]=(short)f2bf(f0.w);
  p[4]=(short)f2bf(f1.x); p[5]=(short)f2bf(f1.y); p[6]=(short)f2bf(f1.z); p[7]=(short)f2bf(f1.w);
  *(bf16x8*)(Wf + (size_t)idx*8) = p;
}

// ---------------- K6: QKV projection — pure-MFMA, no LDS in K-loop ----------
__global__ __launch_bounds__(256) void k_qkv_mfma(
    const unsigned short* __restrict__ xgT, const unsigned short* __restrict__ Wf,
    const float* __restrict__ bq, const float* __restrict__ bk, const float* __restrict__ bv,
    unsigned short* __restrict__ Qbf, unsigned short* __restrict__ Kbf,
    float* __restrict__ Vf) {
  __shared__ float Cb[64*132];                    // padded bounce tile (33.8 KB)
  int mt = blockIdx.x;                            // 0..12: n-tiles 4mt..4mt+3
  int yb = blockIdx.y;                            // 0..11: mat=yb>>2, c0=(yb&3)*128
  int b  = blockIdx.z;
  int mat = yb >> 2;
  int c0 = (yb & 3) * 128;
  int t = threadIdx.x, w = t >> 6, ln = t & 63;
  const unsigned short* Ab = xgT + (size_t)b*NTILE*8192;
  const unsigned short* Bb = Wf + (size_t)mat*32*8192;
  int ctg0 = (c0 >> 4) + w*2;
  f32x4 acc[4][2];
  #pragma unroll
  for (int m = 0; m < 4; m++)
    #pragma unroll
    for (int c2 = 0; c2 < 2; c2++) acc[m][c2] = (f32x4){0.f,0.f,0.f,0.f};
  int ntc[4];
  #pragma unroll
  for (int m = 0; m < 4; m++) { int nt = 4*mt + m; ntc[m] = (nt > 48) ? 48 : nt; }
  for (int s = 0; s < 16; s++) {
    bf16x8 bf0 = *(const bf16x8*)(Bb + (size_t)(ctg0*16 + s)*512 + ln*8);
    bf16x8 bf1 = *(const bf16x8*)(Bb + (size_t)((ctg0+1)*16 + s)*512 + ln*8);
    bf16x8 af[4];
    #pragma unroll
    for (int m = 0; m < 4; m++)
      af[m] = *(const bf16x8*)(Ab + (size_t)(ntc[m]*16 + s)*512 + ln*8);
    #pragma unroll
    for (int m = 0; m < 4; m++) {
      acc[m][0] = __builtin_amdgcn_mfma_f32_16x16x32_bf16(af[m], bf0, acc[m][0], 0,0,0);
      acc[m][1] = __builtin_amdgcn_mfma_f32_16x16x32_bf16(af[m], bf1, acc[m][1], 0,0,0);
    }
  }
  #pragma unroll
  for (int m = 0; m < 4; m++)
    #pragma unroll
    for (int c2 = 0; c2 < 2; c2++)
      #pragma unroll
      for (int r = 0; r < 4; r++)
        Cb[(m*16 + (ln>>4)*4 + r)*132 + w*32 + c2*16 + (ln&15)] = acc[m][c2][r];
  __syncthreads();
  const float* bias = (mat==0)? bq : (mat==1)? bk : bv;
  #pragma unroll
  for (int i = 0; i < 4; i++) {
    int p = w*4 + i;                              // 16 (ntl, sl) pairs
    int ntl = p >> 2, sl = p & 3;
    int nt = 4*mt + ntl;
    if (nt > 48) continue;
    int row = ntl*16 + (ln & 15);
    int col = sl*32 + (ln >> 4)*8;
    float v[8];
    #pragma unroll
    for (int j = 0; j < 8; j++) v[j] = Cb[row*132 + col + j] + bias[c0 + col + j];
    int token = nt*16 + (ln & 15);
    int h = (c0 >> 6) + (sl >> 1);
    int bh = b*NHD + h;
    if (mat < 2) {
      bf16x8 pk;
      #pragma unroll
      for (int j = 0; j < 8; j++) pk[j] = (short)f2bf(v[j]);
      unsigned short* Out = (mat == 0) ? Qbf : Kbf;
      *(bf16x8*)(Out + ((size_t)bh*NTILE + nt)*1024 + (size_t)(sl & 1)*512 + ln*8) = pk;
    } else {
      int d = (sl & 1)*32 + (ln >> 4)*8;
      float* dst = Vf + ((size_t)bh*NT + token)*HD + d;
      *(float4*)dst = make_float4(v[0], v[1], v[2], v[3]);
      *(float4*)(dst + 4) = make_float4(v[4], v[5], v[6], v[7]);
    }
  }
}

// ---------------- K7: MFMA attention, LDS-staged fragments ------------------
// abar[bh,d] = (1/N) sum_m w[m] V[m,d],  w[m] = sum_n exp(s_nm)/l_n
// grid 1024 1-D: bh = blk&127 (same-bh blocks 128 apart -> same XCD L2),
// g8 = blk>>7 picks the Q n-group. 29 KB LDS -> 4 blocks/CU, fully resident.
__global__ __launch_bounds__(256, 4) void k_attn3(const unsigned short* __restrict__ Qbf,
    const unsigned short* __restrict__ Kbf, float* __restrict__ wsum) {
  __shared__ __align__(16) unsigned short Qs[7*1024];
  __shared__ __align__(16) unsigned short Ks[7*1024];
  __shared__ float l_lds[7*16];
  const int qb0[9] = {0,7,13,19,25,31,37,43,49};
  int bh = blockIdx.x & 127, g8 = blockIdx.x >> 7;
  int t = threadIdx.x, w = t >> 6, ln = t & 63;
  int nt0 = qb0[g8], ntq = qb0[g8+1] - nt0;
  const float4* Qg = (const float4*)(Qbf + (size_t)bh*NTILE*1024);
  const float4* Kg = (const float4*)(Kbf + (size_t)bh*NTILE*1024);
  for (int c = t; c < ntq*128; c += 256) ((float4*)Qs)[c] = Qg[nt0*128 + c];
  __syncthreads();
  int lqA = w;
  bool hasB = (w + 4) < ntq;
  int lqB = hasB ? (w + 4) : w;
  bf16x8 qA0 = *(const bf16x8*)(Qs + lqA*1024 + ln*8);
  bf16x8 qA1 = *(const bf16x8*)(Qs + lqA*1024 + 512 + ln*8);
  bf16x8 qB0 = *(const bf16x8*)(Qs + lqB*1024 + ln*8);
  bf16x8 qB1 = *(const bf16x8*)(Qs + lqB*1024 + 512 + ln*8);

  // ---- pass 1: l_n ---------------------------------------------------------
  float lA[4] = {0.f,0.f,0.f,0.f}, lB[4] = {0.f,0.f,0.f,0.f};
  for (int ch = 0; ch < 7; ch++) {
    __syncthreads();
    for (int c = t; c < 7*128; c += 256) ((float4*)Ks)[c] = Kg[ch*7*128 + c];
    __syncthreads();
    #pragma unroll
    for (int mt = 0; mt < 7; mt++) {
      bf16x8 k0 = *(const bf16x8*)(Ks + mt*1024 + ln*8);
      bf16x8 k1 = *(const bf16x8*)(Ks + mt*1024 + 512 + ln*8);
      f32x4 a = {0.f,0.f,0.f,0.f};
      a = __builtin_amdgcn_mfma_f32_16x16x32_bf16(qA0, k0, a, 0,0,0);
      a = __builtin_amdgcn_mfma_f32_16x16x32_bf16(qA1, k1, a, 0,0,0);
      f32x4 cc = {0.f,0.f,0.f,0.f};
      cc = __builtin_amdgcn_mfma_f32_16x16x32_bf16(qB0, k0, cc, 0,0,0);
      cc = __builtin_amdgcn_mfma_f32_16x16x32_bf16(qB1, k1, cc, 0,0,0);
      #pragma unroll
      for (int r = 0; r < 4; r++) {
        lA[r] += __expf(a[r]*0.125f);
        lB[r] += __expf(cc[r]*0.125f);
      }
    }
  }
  #pragma unroll
  for (int r = 0; r < 4; r++) {
    float v = lA[r];
    v += __shfl_xor(v,1,64); v += __shfl_xor(v,2,64);
    v += __shfl_xor(v,4,64); v += __shfl_xor(v,8,64);
    if ((ln & 15) == 0) l_lds[lqA*16 + (ln>>4)*4 + r] = v;
    float u = lB[r];
    u += __shfl_xor(u,1,64); u += __shfl_xor(u,2,64);
    u += __shfl_xor(u,4,64); u += __shfl_xor(u,8,64);
    if (hasB && (ln & 15) == 0) l_lds[lqB*16 + (ln>>4)*4 + r] = u;
  }
  __syncthreads();
  if (t < ntq*16) l_lds[t] = 1.f / l_lds[t];
  __syncthreads();
  float rl[7];
  #pragma unroll
  for (int j = 0; j < 7; j++) rl[j] = l_lds[(j < ntq ? j : 0)*16 + (ln & 15)];

  // ---- pass 2: w_m partials (A=K, B=Q) ------------------------------------
  for (int ch = 0; ch < 7; ch++) {
    __syncthreads();
    for (int c = t; c < 7*128; c += 256) ((float4*)Ks)[c] = Kg[ch*7*128 + c];
    __syncthreads();
    for (int ml = w; ml < 7; ml += 4) {
      bf16x8 a0 = *(const bf16x8*)(Ks + ml*1024 + ln*8);
      bf16x8 a1 = *(const bf16x8*)(Ks + ml*1024 + 512 + ln*8);
      float w0 = 0.f, w1 = 0.f, w2 = 0.f, w3 = 0.f;
      #pragma unroll
      for (int j = 0; j < 7; j++) {
        if (j < ntq) {
          bf16x8 b0 = *(const bf16x8*)(Qs + j*1024 + ln*8);
          bf16x8 b1 = *(const bf16x8*)(Qs + j*1024 + 512 + ln*8);
          f32x4 a = {0.f,0.f,0.f,0.f};
          a = __builtin_amdgcn_mfma_f32_16x16x32_bf16(a0, b0, a, 0,0,0);
          a = __builtin_amdgcn_mfma_f32_16x16x32_bf16(a1, b1, a, 0,0,0);
          float r = rl[j];
          w0 += __expf(a[0]*0.125f) * r;
          w1 += __expf(a[1]*0.125f) * r;
          w2 += __expf(a[2]*0.125f) * r;
          w3 += __expf(a[3]*0.125f) * r;
        }
      }
      w0 += __shfl_xor(w0,1,64); w0 += __shfl_xor(w0,2,64); w0 += __shfl_xor(w0,4,64); w0 += __shfl_xor(w0,8,64);
      w1 += __shfl_xor(w1,1,64); w1 += __shfl_xor(w1,2,64); w1 += __shfl_xor(w1,4,64); w1 += __shfl_xor(w1,8,64);
      w2 += __shfl_xor(w2,1,64); w2 += __shfl_xor(w2,2,64); w2 += __shfl_xor(w2,4,64); w2 += __shfl_xor(w2,8,64);
      w3 += __shfl_xor(w3,1,64); w3 += __shfl_xor(w3,2,64); w3 += __shfl_xor(w3,4,64); w3 += __shfl_xor(w3,8,64);
      if ((ln & 15) == 0) {
        int m = (ch*7 + ml)*16 + (ln>>4)*4;
        atomicAdd(&wsum[bh*NT + m + 0], w0);
        atomicAdd(&wsum[bh*NT + m + 1], w1);
        atomicAdd(&wsum[bh*NT + m + 2], w2);
        atomicAdd(&wsum[bh*NT + m + 3], w3);
      }
    }
  }
}

// ---- K7c: abar[bh,d] = (1/N) sum_m w_m V[m,d] ------------------------------
__global__ void k_attn_av(const float* __restrict__ w, const float* __restrict__ Vm,
                          float* __restrict__ abar) {
  __shared__ float red[256];
  int bh = blockIdx.x, t = threadIdx.x;
  int d = t & 63, chunk = t >> 6;                 // 4 chunks of 196 keys
  float acc = 0.f;
  const float* vb = Vm + (size_t)bh*NT*HD;
  const float* wb = w + bh*NT;
  for (int m = chunk*196; m < (chunk+1)*196; m++)
    acc += wb[m] * vb[(size_t)m*HD + d];
  red[t] = acc;
  __syncthreads();
  if (t < 64)
    abar[bh*HD + t] = (red[t] + red[64+t] + red[128+t] + red[192+t]) * (1.f/NT);
}

// --------- K8: pooled head, parallelized ------------------------------------
// A: pv[b][c] = bo[c] + p1[b][c] + sum_j abar[b][j]*wo[c][j]   (wave per c)
__global__ void k_headA(const float* __restrict__ p1, const float* __restrict__ abar,
                        const float* __restrict__ wo, const float* __restrict__ bo,
                        float* __restrict__ pv) {
  int b = blockIdx.x, cg = blockIdx.y;
  int t = threadIdx.x, w = t >> 6, ln = t & 63;
  float a[8];
  #pragma unroll
  for (int k = 0; k < 8; k++) a[k] = abar[b*CC + ln + 64*k];
  int c0 = cg*64 + w*16;
  for (int i = 0; i < 16; i++) {
    int c = c0 + i;
    const float* wr = wo + (size_t)c*CC;
    float s = 0.f;
    #pragma unroll
    for (int k = 0; k < 8; k++) s += a[k] * wr[ln + 64*k];
    for (int o = 32; o; o >>= 1) s += __shfl_down(s, o, 64);
    if (ln == 0) pv[b*CC + c] = s + bo[c] + p1[b*CC + c];
  }
}

// B: LayerNorm per batch row (one wave per b)
__global__ void k_headB(const float* __restrict__ pv, const float* __restrict__ ln_g,
                        const float* __restrict__ ln_b, float* __restrict__ lnv) {
  int b = blockIdx.x, ln = threadIdx.x;
  float v[8], s = 0.f, s2 = 0.f;
  #pragma unroll
  for (int k = 0; k < 8; k++) { v[k] = pv[b*CC + ln + 64*k]; s += v[k]; s2 += v[k]*v[k]; }
  for (int o = 32; o; o >>= 1) { s += __shfl_down(s, o, 64); s2 += __shfl_down(s2, o, 64); }
  s = __shfl(s, 0, 64); s2 = __shfl(s2, 0, 64);
  float mean = s * (1.f/CC);
  float rs = rsqrtf(s2*(1.f/CC) - mean*mean + 1e-5f);
  #pragma unroll
  for (int k = 0; k < 8; k++) {
    int c = ln + 64*k;
    lnv[b*CC + c] = (v[k]-mean)*rs*ln_g[c] + ln_b[c];
  }
}

// C: h1[b][j] = relu(fc1_b[j] + sum_c lnv[b][c]*fc1_w[j][c])
__global__ void k_headC(const float* __restrict__ lnv, const float* __restrict__ fc1_w,
                        const float* __restrict__ fc1_b, float* __restrict__ h1) {
  int b = blockIdx.x, cg = blockIdx.y;
  int t = threadIdx.x, w = t >> 6, ln = t & 63;
  float a[8];
  #pragma unroll
  for (int k = 0; k < 8; k++) a[k] = lnv[b*CC + ln + 64*k];
  int c0 = cg*64 + w*16;
  for (int i = 0; i < 16; i++) {
    int c = c0 + i;
    const float* wr = fc1_w + (size_t)c*CC;
    float s = 0.f;
    #pragma unroll
    for (int k = 0; k < 8; k++) s += a[k] * wr[ln + 64*k];
    for (int o = 32; o; o >>= 1) s += __shfl_down(s, o, 64);
    if (ln == 0) h1[b*CC + c] = fmaxf(s + fc1_b[c], 0.f);
  }
}

// D: out[b] = fc2_b + h1[b] . fc2_w  (one wave per b)
__global__ void k_headD(const float* __restrict__ h1, const float* __restrict__ fc2_w,
                        const float* __restrict__ fc2_b, float* __restrict__ out) {
  int b = blockIdx.x, ln = threadIdx.x;
  float s = 0.f;
  #pragma unroll
  for (int k = 0; k < 8; k++) s += h1[b*CC + ln + 64*k] * fc2_w[ln + 64*k];
  for (int o = 32; o; o >>= 1) s += __shfl_down(s, o, 64);
  if (ln == 0) out[b] = s + fc2_b[0];
}

extern "C" void kernel_launch(void* const* d_in, const int* in_sizes, int n_in,
                              void* d_out, int out_size, void* d_ws, size_t ws_size,
                              hipStream_t stream) {
  const float* x       = (const float*)d_in[0];
  const float* mlp_w1  = (const float*)d_in[1];
  const float* mlp_b1  = (const float*)d_in[2];
  const float* mlp_w2  = (const float*)d_in[3];
  const float* mlp_b2  = (const float*)d_in[4];
  const float* sp_w    = (const float*)d_in[5];
  const float* sp_g    = (const float*)d_in[6];
  const float* sp_b    = (const float*)d_in[7];
  const float* sp_mu   = (const float*)d_in[8];
  const float* sp_var  = (const float*)d_in[9];
  const float* wq      = (const float*)d_in[10];
  const float* bq      = (const float*)d_in[11];
  const float* wk      = (const float*)d_in[12];
  const float* bk      = (const float*)d_in[13];
  const float* wv      = (const float*)d_in[14];
  const float* bv      = (const float*)d_in[15];
  const float* wo      = (const float*)d_in[16];
  const float* bo      = (const float*)d_in[17];
  const float* ln_g    = (const float*)d_in[18];
  const float* ln_b    = (const float*)d_in[19];
  const float* fc1_w   = (const float*)d_in[20];
  const float* fc1_b   = (const float*)d_in[21];
  const float* fc2_w   = (const float*)d_in[22];
  const float* fc2_b   = (const float*)d_in[23];

  float* ws = (float*)d_ws;
  float* avg_p = ws + OFS_AVGP;
  float* max_p = ws + OFS_MAXP;
  float* chs   = ws + OFS_CHS;
  float* cmax  = ws + OFS_CMAX;
  float* cmean = ws + OFS_CMEAN;
  float* sp    = ws + OFS_SP;
  float* p1    = ws + OFS_P1;
  float* abar  = ws + OFS_ABAR;
  unsigned short* xgT = (unsigned short*)(ws + OFS_XGT);
  unsigned short* Qbf = (unsigned short*)(ws + OFS_QBF);
  unsigned short* Kbf = (unsigned short*)(ws + OFS_KBF);
  float* Vf    = ws + OFS_V2;
  unsigned short* Wf  = (unsigned short*)(ws + OFS_WF);
  float* wsum  = ws + OFS_W;
  float* pv    = ws + OFS_PV;
  float* lnv   = ws + OFS_LNV;
  float* h1    = ws + OFS_H1;

  hipMemsetAsync(p1, 0, BB*CC*sizeof(float), stream);
  hipMemsetAsync(wsum, 0, BB*NHD*NT*sizeof(float), stream);

  k_pool   <<<2048, 256, 0, stream>>>(x, avg_p, max_p);
  k_chmlp  <<<BB, 256, 0, stream>>>(avg_p, max_p, mlp_w1, mlp_b1, mlp_w2, mlp_b2, chs);
  k_chgate2<<<dim3(BB,4), 256, 0, stream>>>(x, chs, cmax, cmean);
  k_spconv <<<dim3(BB,4), 256, 0, stream>>>(cmax, cmean, sp_w, sp_g, sp_b, sp_mu, sp_var, sp);
  k_wfrag  <<<384, 256, 0, stream>>>(wq, wk, wv, Wf);
  k_sfuse  <<<dim3(NTILE,BB), 256, 0, stream>>>(x, chs, sp, xgT, p1);
  k_qkv_mfma<<<dim3(13,12,BB), 256, 0, stream>>>(xgT, Wf, bq, bk, bv, Qbf, Kbf, Vf);
  k_attn3  <<<1024, 256, 0, stream>>>(Qbf, Kbf, wsum);
  k_attn_av<<<128, 256, 0, stream>>>(wsum, Vf, abar);
  k_headA  <<<dim3(BB,8), 256, 0, stream>>>(p1, abar, wo, bo, pv);
  k_headB  <<<BB, 64, 0, stream>>>(pv, ln_g, ln_b, lnv);
  k_headC  <<<dim3(BB,8), 256, 0, stream>>>(lnv, fc1_w, fc1_b, h1);
  k_headD  <<<BB, 64, 0, stream>>>(h1, fc2_w, fc2_b, (float*)d_out);
}